// Round 12
// baseline (120.831 us; speedup 1.0000x reference)
//
#include <hip/hip_runtime.h>

typedef __attribute__((ext_vector_type(8))) short short8;
typedef __attribute__((ext_vector_type(4))) short s4v;
typedef __attribute__((ext_vector_type(4))) float f32x4;
typedef unsigned short u16;
typedef unsigned int u32;
typedef unsigned long long u64;

#define TAU_F 0.3f

__device__ __forceinline__ u16 f2bf(float f){
  u32 u = __float_as_uint(f);
  u32 r = u + 0x7FFFu + ((u >> 16) & 1u);
  return (u16)(r >> 16);
}
__device__ __forceinline__ float bf2f(u16 v){
  return __uint_as_float(((u32)v) << 16);
}
__device__ __forceinline__ float tanh_fast(float x){
  const float e = __expf(2.f * x);
  return 1.f - 2.f / (e + 1.f);
}

typedef __attribute__((address_space(1))) const u32 glb_u32;
typedef __attribute__((address_space(3))) u32 lds_u32;
__device__ __forceinline__ void async_lds16(const void* g, void* l){
  __builtin_amdgcn_global_load_lds((glb_u32*)g, (lds_u32*)l, 16, 0, 0);
}

// ---------------- merged preprocessing (one launch) --------------------------
__global__ __launch_bounds__(1024)
void pre_kernel(float* __restrict__ out, float* __restrict__ scores,
                const float* __restrict__ W0, u16* __restrict__ w0t,
                const float* __restrict__ W1, u16* __restrict__ w1t,
                const float* __restrict__ S1W, u16* __restrict__ s1t,
                const float* __restrict__ wed0, const float* __restrict__ aed0,
                const float* __restrict__ wed1, const float* __restrict__ aed1,
                float* __restrict__ aeb,
                const float* __restrict__ asrc0, const float* __restrict__ adst0,
                const float* __restrict__ asrc1, const float* __restrict__ adst1,
                float* __restrict__ u0, float* __restrict__ v0,
                float* __restrict__ u1, float* __restrict__ v1,
                const int* __restrict__ mask, int* __restrict__ cnt, int* __restrict__ idxb)
{
  __shared__ float lds[64*65];
  const int blk = blockIdx.x, t = threadIdx.x;

  auto tr_tile = [&](const float* in, u16* o, int K, int N, int kt, int ntile) {
    const int r = t >> 4, c0 = (t & 15) * 4;
    const int k0 = kt*64, n0 = ntile*64;
    const float4 v = *(const float4*)&in[(long)(k0 + r)*N + n0 + c0];
    lds[r*65 + c0 + 0] = v.x; lds[r*65 + c0 + 1] = v.y;
    lds[r*65 + c0 + 2] = v.z; lds[r*65 + c0 + 3] = v.w;
    __syncthreads();
    const u64 pk = (u64)f2bf(lds[(c0+0)*65 + r])
                 | ((u64)f2bf(lds[(c0+1)*65 + r]) << 16)
                 | ((u64)f2bf(lds[(c0+2)*65 + r]) << 32)
                 | ((u64)f2bf(lds[(c0+3)*65 + r]) << 48);
    *(u64*)&o[(long)(n0 + r)*K + k0 + c0] = pk;
  };

  if (blk < 16)  { out[blk*1024 + t] = 0.f; return; }
  if (blk < 32)  { scores[(blk-16)*1024 + t] = 0.f; return; }
  if (blk < 56)  { const int id = blk-32;  tr_tile(W0,  w0t, 768, 128, id >> 1, id & 1); return; }
  if (blk < 60)  { const int id = blk-56;  tr_tile(W1,  w1t, 128, 128, id >> 1, id & 1); return; }
  if (blk < 188) { const int id = blk-60;  tr_tile(S1W, s1t, 1024, 512, id >> 3, id & 7); return; }
  if (blk == 188) {
    if (t < 128) { lds[t] = wed0[t]*aed0[t]; lds[128+t] = wed1[t]*aed1[t]; }
    __syncthreads();
    for (int o = 64; o > 0; o >>= 1) { if (t < o) { lds[t] += lds[t+o]; lds[128+t] += lds[128+t+o]; } __syncthreads(); }
    if (t == 0) { aeb[0] = lds[0]; aeb[1] = lds[128]; }
    return;
  }
  if (blk == 189) {
    if (t < 768) {
      float su = 0.f, sv = 0.f;
      for (int c = 0; c < 128; c++) { const float w = W0[t*128 + c]; su += w*asrc0[c]; sv += w*adst0[c]; }
      u0[t] = su; v0[t] = sv;
    }
    return;
  }
  if (blk == 190) {
    if (t < 128) {
      float su = 0.f, sv = 0.f;
      for (int k = 0; k < 128; k++) { const float w = W1[k*128 + t]; su += w*asrc1[k]; sv += w*adst1[k]; }
      u1[t] = su; v1[t] = sv;
    }
    return;
  }
  { // compaction
    int* wtot = (int*)lds;
    int* woff = (int*)lds + 16;
    const int b = blk - 191;
    const int w = t >> 6, lane = t & 63;
    const int m = mask[(b << 10) + t];
    const u64 bal = __ballot(m != 0);
    const int pos = __popcll(bal & ((1ull << lane) - 1ull));
    if (lane == 0) wtot[w] = __popcll(bal);
    __syncthreads();
    if (t == 0) { int a = 0; for (int i = 0; i < 16; i++) { woff[i] = a; a += wtot[i]; } cnt[b] = a; }
    __syncthreads();
    if (m) idxb[(b << 10) + woff[w] + pos] = t;
  }
}

// ---- gather (no normalize store), rnorm, fused layer-0 als/ald --------------
__global__ __launch_bounds__(256)
void hn_kernel(const float* __restrict__ hidden, const int* __restrict__ cnt,
               const int* __restrict__ idx,
               const float* __restrict__ u0, const float* __restrict__ v0,
               const float* __restrict__ aeb,
               u16* __restrict__ hallc, float* __restrict__ rnp,
               float* __restrict__ als, float* __restrict__ ald)
{
  const int gr = blockIdx.x * 4 + (threadIdx.x >> 6);
  const int b = gr >> 10, c = gr & 1023;
  const int lane = threadIdx.x & 63;
  if (c >= cnt[b]) return;
  const int l = idx[gr];
  const float* h = hidden + (long)((b << 10) + l) * 768;
  float x[12]; float ss = 0.f, sa = 0.f, sd = 0.f;
#pragma unroll
  for (int k = 0; k < 12; k++) {
    x[k] = h[k*64 + lane];
    ss += x[k]*x[k];
    sa += x[k]*u0[k*64 + lane];
    sd += x[k]*v0[k*64 + lane];
  }
#pragma unroll
  for (int o = 32; o > 0; o >>= 1) {
    ss += __shfl_xor(ss, o, 64);
    sa += __shfl_xor(sa, o, 64);
    sd += __shfl_xor(sd, o, 64);
  }
  const float inv = 1.f / fmaxf(sqrtf(ss), 1e-8f);
  if (lane == 0) { als[gr] = sa; ald[gr] = sd + aeb[0]; rnp[gr] = inv; }
#pragma unroll
  for (int k = 0; k < 12; k++)
    hallc[(long)gr*1024 + k*64 + lane] = f2bf(x[k]);
}

// ------- mega GEMM launch: 128x64 tiles, BK=64, dbuf, XOR-swizzled -----------
// [0,1152): sim upper-band tiles (XCD-pinned per batch; rn-scaled, elem mirror)
// [1152,1408): proj0 (hallc @ w0t -> gt)
// [1408,2432): scorer_p0 (hallc[:,0:768] @ s1t[:,0:768] -> bf16 partial)
__global__ __launch_bounds__(256)
void mega_kernel(const u16* __restrict__ hallc, const u16* __restrict__ w0t,
                 const u16* __restrict__ s1t, const float* __restrict__ rn,
                 unsigned char* __restrict__ adjp, u16* __restrict__ gtp,
                 u16* __restrict__ partial, const int* __restrict__ cnt)
{
  __shared__ u16 lA[2][128*64];
  __shared__ u16 lB[2][64*64];
  const int t = threadIdx.x, w = t >> 6, lane = t & 63;
  const int bid = blockIdx.x;
  int mode, bz = 0, i0, n0, lda, ldb, cb = 0;
  const u16 *Ab, *Bb;
  if (bid < 1152) {
    mode = 0;
    const int xcd = bid & 7, s = bid >> 3;          // s: 0..143
    const int hi = (s >= 72) ? 1 : 0;
    bz = xcd*2 + hi;
    int rem = s - hi*72, width = 16, ti = 0;
    while (rem >= width) { rem -= width; ti++; width -= 2; }
    const int tj = 2*ti + rem;
    i0 = ti*128; n0 = tj*64;                        // n0 >= i0
    cb = cnt[bz];
    if (i0 >= cb || n0 >= cb) return;
    Ab = hallc + ((long)bz << 20);
    Bb = Ab; lda = 1024; ldb = 1024;
  } else if (bid < 1408) {
    mode = 1;
    const int id = bid - 1152;                      // 0..255
    const int y = (id & 7) + ((id >> 4) << 3);
    i0 = y * 128; n0 = ((id >> 3) & 1) * 64;
    if ((i0 & 1023) >= cnt[i0 >> 10]) return;
    Ab = hallc; lda = 1024; Bb = w0t; ldb = 768;
  } else {
    mode = 2;
    const int id = bid - 1408;                      // 0..1023
    const int y = (id & 7) + ((id >> 6) << 3);
    i0 = y * 128; n0 = ((id >> 3) & 7) * 64;
    if ((i0 & 1023) >= cnt[i0 >> 10]) return;
    Ab = hallc; lda = 1024; Bb = s1t; ldb = 1024;
  }
  const int srow = t >> 3, scg = t & 7;
  const int sc0 = ((scg ^ (srow & 7)) << 3);
  const int rA = lane & 15, kg = lane >> 4;
  const int sw = rA & 7;
  const int off0 = ((kg ^ sw) << 3);
  const int off1 = (((4 + kg) ^ sw) << 3);
  f32x4 acc[2][4] = {};

  auto stage = [&](int buf, int kt) {
#pragma unroll
    for (int q = 0; q < 4; q++)
      async_lds16(Ab + (long)(i0 + srow + q*32) * lda + kt + sc0, &lA[buf][q*2048 + t*8]);
#pragma unroll
    for (int q = 0; q < 2; q++)
      async_lds16(Bb + (long)(n0 + srow + q*32) * ldb + kt + sc0, &lB[buf][q*2048 + t*8]);
  };
  auto compute = [&](int buf) {
    short8 a[2][2], b[4][2];
#pragma unroll
    for (int m = 0; m < 2; m++) {
      const int ra = (w*32 + m*16 + rA) * 64;
      a[m][0] = *(const short8*)&lA[buf][ra + off0];
      a[m][1] = *(const short8*)&lA[buf][ra + off1];
    }
#pragma unroll
    for (int n = 0; n < 4; n++) {
      const int rb = (n*16 + rA) * 64;
      b[n][0] = *(const short8*)&lB[buf][rb + off0];
      b[n][1] = *(const short8*)&lB[buf][rb + off1];
    }
#pragma unroll
    for (int m = 0; m < 2; m++)
#pragma unroll
      for (int n = 0; n < 4; n++) {
        acc[m][n] = __builtin_amdgcn_mfma_f32_16x16x32_bf16(a[m][0], b[n][0], acc[m][n], 0, 0, 0);
        acc[m][n] = __builtin_amdgcn_mfma_f32_16x16x32_bf16(a[m][1], b[n][1], acc[m][n], 0, 0, 0);
      }
  };

  stage(0, 0);
  __syncthreads();
  int cur = 0;
  for (int kt = 1; kt < 12; kt++) {
    stage(cur ^ 1, kt << 6);
    compute(cur);
    __syncthreads();
    cur ^= 1;
  }
  compute(cur);

#pragma unroll
  for (int m = 0; m < 2; m++) {
    const int gi0 = i0 + w*32 + m*16 + kg*4;
#pragma unroll
    for (int n = 0; n < 4; n++) {
      const int gj = n0 + n*16 + rA;
#pragma unroll
      for (int r = 0; r < 4; r++) {
        const int gi = gi0 + r;
        const float c = acc[m][n][r];
        if (mode == 0) {
          if (gi < cb && gj < cb) {
            const float sim = c * rn[(bz << 10) + gi] * rn[(bz << 10) + gj];
            const unsigned char e = (sim > TAU_F) ? 1 : 0;
            adjp[((long)bz << 20) + ((long)gi << 10) + gj] = e;
            if (gi < gj) adjp[((long)bz << 20) + ((long)gj << 10) + gi] = e;
          }
        } else if (mode == 1) {
          const int b = gi >> 10, l = gi & 1023;
          gtp[(((long)(b*128 + gj)) << 10) + l] = f2bf(c);
        } else {
          partial[(long)gi * 512 + gj] = f2bf(c);
        }
      }
    }
  }
}

// ------- scorer finisher: K=256 (h1|h2 slice) + partial + tanh + S2 dot ------
__global__ __launch_bounds__(256)
void scorer_fin(const u16* __restrict__ hallc, const u16* __restrict__ s1t,
                const u16* __restrict__ partial, const int* __restrict__ cnt,
                const float* __restrict__ s1b, const float* __restrict__ s2w,
                float* __restrict__ scoresp)
{
  __shared__ u16 lA[2][64*64];
  __shared__ u16 lB[2][64*64];
  __shared__ float sgrid[64];
  const int t = threadIdx.x, w = t >> 6, lane = t & 63;
  const int id = blockIdx.x;
  const int i0 = (((id & 7) << 5) + ((id >> 3) & 31)) * 64;
  const int n0 = (id >> 8) * 64;
  if ((i0 & 1023) >= cnt[i0 >> 10]) return;
  if (t < 64) sgrid[t] = 0.f;
  const int wr = w >> 1, wc = w & 1;
  const int srow = t >> 3, scg = t & 7;
  const int sc0 = ((scg ^ (srow & 7)) << 3);
  const long arow0 = (long)(i0 + srow) * 1024 + 768, arow1 = (long)(i0 + srow + 32) * 1024 + 768;
  const long brow0 = (long)(n0 + srow) * 1024 + 768, brow1 = (long)(n0 + srow + 32) * 1024 + 768;
  const int rA = lane & 15, kg = lane >> 4;
  const int sw = rA & 7;
  const int off0 = ((kg ^ sw) << 3);
  const int off1 = (((4 + kg) ^ sw) << 3);
  const int rowA0 = (wr*32 + rA) * 64, rowA1 = (wr*32 + 16 + rA) * 64;
  const int rowB0 = (wc*32 + rA) * 64, rowB1 = (wc*32 + 16 + rA) * 64;
  f32x4 acc[2][2] = {};

  auto stage = [&](int buf, int kt) {
    async_lds16(hallc + arow0 + kt + sc0, &lA[buf][t*8]);
    async_lds16(hallc + arow1 + kt + sc0, &lA[buf][2048 + t*8]);
    async_lds16(s1t + brow0 + kt + sc0, &lB[buf][t*8]);
    async_lds16(s1t + brow1 + kt + sc0, &lB[buf][2048 + t*8]);
  };
  auto compute = [&](int buf) {
    short8 a00 = *(const short8*)&lA[buf][rowA0 + off0];
    short8 a01 = *(const short8*)&lA[buf][rowA0 + off1];
    short8 a10 = *(const short8*)&lA[buf][rowA1 + off0];
    short8 a11 = *(const short8*)&lA[buf][rowA1 + off1];
    short8 b00 = *(const short8*)&lB[buf][rowB0 + off0];
    short8 b01 = *(const short8*)&lB[buf][rowB0 + off1];
    short8 b10 = *(const short8*)&lB[buf][rowB1 + off0];
    short8 b11 = *(const short8*)&lB[buf][rowB1 + off1];
    acc[0][0] = __builtin_amdgcn_mfma_f32_16x16x32_bf16(a00, b00, acc[0][0], 0, 0, 0);
    acc[0][1] = __builtin_amdgcn_mfma_f32_16x16x32_bf16(a00, b10, acc[0][1], 0, 0, 0);
    acc[1][0] = __builtin_amdgcn_mfma_f32_16x16x32_bf16(a10, b00, acc[1][0], 0, 0, 0);
    acc[1][1] = __builtin_amdgcn_mfma_f32_16x16x32_bf16(a10, b10, acc[1][1], 0, 0, 0);
    acc[0][0] = __builtin_amdgcn_mfma_f32_16x16x32_bf16(a01, b01, acc[0][0], 0, 0, 0);
    acc[0][1] = __builtin_amdgcn_mfma_f32_16x16x32_bf16(a01, b11, acc[0][1], 0, 0, 0);
    acc[1][0] = __builtin_amdgcn_mfma_f32_16x16x32_bf16(a11, b01, acc[1][0], 0, 0, 0);
    acc[1][1] = __builtin_amdgcn_mfma_f32_16x16x32_bf16(a11, b11, acc[1][1], 0, 0, 0);
  };

  stage(0, 0);
  __syncthreads();
  int cur = 0;
  for (int kt = 1; kt < 4; kt++) {
    stage(cur ^ 1, kt << 6);
    compute(cur);
    __syncthreads();
    cur ^= 1;
  }
  compute(cur);

#pragma unroll
  for (int m = 0; m < 2; m++)
#pragma unroll
    for (int r = 0; r < 4; r++) {
      const int gi = i0 + wr*32 + m*16 + kg*4 + r;
      float contrib = 0.f;
#pragma unroll
      for (int n = 0; n < 2; n++) {
        const int gj = n0 + wc*32 + n*16 + rA;
        const float p = acc[m][n][r] + bf2f(partial[(long)gi*512 + gj]) + s1b[gj];
        contrib += tanh_fast(p) * s2w[gj];
      }
#pragma unroll
      for (int off = 1; off < 16; off <<= 1) contrib += __shfl_xor(contrib, off, 64);
      if (rA == 0) atomicAdd(&sgrid[wr*32 + m*16 + kg*4 + r], contrib);
    }
  __syncthreads();
  if (t < 64) {
    const int gi = i0 + t;
    if ((gi & 1023) < cnt[gi >> 10]) atomicAdd(&scoresp[gi], sgrid[t]);
  }
}

// ---------------- fused GAT attention; FUSE=1 adds als1/ald1 + proj1->gt2 ----
template<int FUSE>
__global__ __launch_bounds__(256)
void gat_attn(const unsigned char* __restrict__ adj,
              const float* __restrict__ ald, const float* __restrict__ als,
              const u16* __restrict__ gT, const float* __restrict__ bias,
              const int* __restrict__ cnt,
              u16* __restrict__ hall, int hall_off,
              const float* __restrict__ u1, const float* __restrict__ v1,
              const float* __restrict__ aeb1,
              float* __restrict__ als_o, float* __restrict__ ald_o,
              const u16* __restrict__ w1t, u16* __restrict__ gt2)
{
  __shared__ float red[4][16][132];
  __shared__ float ssumw[4][16];
  __shared__ float alds[FUSE ? 16 : 1][17], aldd[FUSE ? 16 : 1][17];
  __shared__ u16 h1s[FUSE ? 16 : 1][136];
  const int t = threadIdx.x, w = t >> 6, lane = t & 63;
  const int o = blockIdx.x;
  const int xcd = o & 7, s = o >> 3;
  const int bz = xcd*2 + (s >> 6);
  const int i0 = (s & 63) * 16;
  const int cb = cnt[bz];
  if (i0 >= cb) return;
  const int rr = lane & 15, kg = lane >> 4;
  const int r0 = i0 + rr;
  const bool rvalid = r0 < cb;
  const float ald0 = ald[(bz << 10) + r0];
  const unsigned char* arow = adj + ((long)bz << 20) + ((long)r0 << 10);
  const float* als_b = als + (bz << 10);
  const u16* gTb = gT + ((long)bz << 17);
  float s0 = 0.f;
  f32x4 acc[8] = {};
  const int jbase = w * 256 + kg * 8;

  u64 aw[8];
#pragma unroll
  for (int it = 0; it < 8; it++) {
    const int jl = jbase + it*32;
    u64 a = 0;
    if (rvalid && jl < cb) {
      a = *(const u64*)(arow + jl);
      const int rem = cb - jl;
      if (rem < 8) a &= (1ull << (rem * 8)) - 1ull;
    }
    aw[it] = a;
  }

#pragma unroll
  for (int it = 0; it < 8; it++) {
    const u64 a0 = aw[it];
    if (__any(a0 != 0ull)) {
      const int jl = jbase + it*32;
      const float4 f0 = *(const float4*)(als_b + jl);
      const float4 f1 = *(const float4*)(als_b + jl + 4);
      const float sv[8] = {f0.x, f0.y, f0.z, f0.w, f1.x, f1.y, f1.z, f1.w};
      short8 pa;
#pragma unroll
      for (int e = 0; e < 8; e++) {
        float x = ald0 + sv[e];
        x = x > 0.f ? x : 0.2f * x;
        const float p = ((a0 >> (8*e)) & 255ull) ? __expf(x) : 0.f;
        s0 += p;
        pa[e] = (short)f2bf(p);
      }
#pragma unroll
      for (int nf = 0; nf < 8; nf++) {
        const short8 b = *(const short8*)&gTb[(long)(nf*16 + rr) * 1024 + jl];
        acc[nf] = __builtin_amdgcn_mfma_f32_16x16x32_bf16(pa, b, acc[nf], 0, 0, 0);
      }
    }
  }

  s0 += __shfl_xor(s0, 16, 64);
  s0 += __shfl_xor(s0, 32, 64);
  if (lane < 16) ssumw[w][lane] = s0;
#pragma unroll
  for (int nf = 0; nf < 8; nf++)
#pragma unroll
    for (int rg = 0; rg < 4; rg++)
      red[w][kg*4 + rg][nf*16 + rr] = acc[nf][rg];
  __syncthreads();

  const int r = t >> 4, c0 = (t & 15) * 8;
  const float sm = ssumw[0][r] + ssumw[1][r] + ssumw[2][r] + ssumw[3][r];
  const float inv = sm > 0.f ? 1.f / sm : 0.f;
  const long gi = ((long)bz << 10) + i0 + r;
  u16* orow = hall + gi * 1024 + hall_off;
  short8 hv;
  float pa_s = 0.f, pa_d = 0.f;
#pragma unroll
  for (int q = 0; q < 8; q++) {
    const int c = c0 + q;
    float v = (red[0][r][c] + red[1][r][c] + red[2][r][c] + red[3][r][c]) * inv + bias[c];
    v = v > 0.f ? v : 0.f;
    hv[q] = (short)f2bf(v);
    if (FUSE) { pa_s += v * u1[c]; pa_d += v * v1[c]; }
  }
  *(short8*)&orow[c0] = hv;
  if (FUSE) {
    *(short8*)&h1s[r][c0] = hv;
    alds[r][t & 15] = pa_s;
    aldd[r][t & 15] = pa_d;
    __syncthreads();
    if (t < 16) {
      float s2 = 0.f, d2 = 0.f;
#pragma unroll
      for (int j = 0; j < 16; j++) { s2 += alds[t][j]; d2 += aldd[t][j]; }
      als_o[(bz << 10) + i0 + t] = s2;
      ald_o[(bz << 10) + i0 + t] = d2 + aeb1[0];
    }
    // proj1: gt2 rows i0..i0+15 = h1s(16x128) @ W1; wave w covers cols [w*32,w*32+32)
    f32x4 pacc[2] = {};
    short8 paf[4];
#pragma unroll
    for (int ks = 0; ks < 4; ks++)
      paf[ks] = *(const short8*)&h1s[lane & 15][ks*32 + kg*8];
#pragma unroll
    for (int n = 0; n < 2; n++) {
      const int col = w*32 + n*16 + (lane & 15);
#pragma unroll
      for (int ks = 0; ks < 4; ks++) {
        const short8 pb = *(const short8*)&w1t[col*128 + ks*32 + kg*8];
        pacc[n] = __builtin_amdgcn_mfma_f32_16x16x32_bf16(paf[ks], pb, pacc[n], 0, 0, 0);
      }
    }
#pragma unroll
    for (int n = 0; n < 2; n++) {
      const int gj = w*32 + n*16 + (lane & 15);
#pragma unroll
      for (int rg = 0; rg < 4; rg++)
        gt2[(((long)(bz*128 + gj)) << 10) + i0 + kg*4 + rg] = f2bf(pacc[n][rg]);
    }
  }
}

// ---------------- pooled: softmax + weighted sum of bf16 hallc rows ----------
__global__ __launch_bounds__(256)
void pooled_kernel(const u16* __restrict__ hallc, const float* __restrict__ scores,
                   const int* __restrict__ cnt, float* __restrict__ out)
{
  __shared__ float tot[4];
  const int b = blockIdx.y, l0 = blockIdx.x * 64, t = threadIdx.x;
  const int cb = cnt[b];
  if (l0 >= cb) return;
  float part = 0.f;
#pragma unroll
  for (int q = 0; q < 4; q++) {
    const int l = q*256 + t;
    if (l < cb) part += __expf(scores[(b << 10) + l]);
  }
#pragma unroll
  for (int o = 32; o > 0; o >>= 1) part += __shfl_xor(part, o, 64);
  if ((t & 63) == 0) tot[t >> 6] = part;
  __syncthreads();
  const float inv = 1.f / fmaxf(tot[0] + tot[1] + tot[2] + tot[3], 1e-16f);

  const int lim = min(64, cb - l0);
  float a0 = 0.f, a1 = 0.f, a2 = 0.f, a3 = 0.f;
  for (int l = 0; l < lim; l++) {
    const int gl = (b << 10) + l0 + l;
    const float wv = __expf(scores[gl]) * inv;
    const s4v v = *(const s4v*)&hallc[(long)gl*1024 + t*4];
    a0 += wv * bf2f((u16)v[0]);
    a1 += wv * bf2f((u16)v[1]);
    a2 += wv * bf2f((u16)v[2]);
    a3 += wv * bf2f((u16)v[3]);
  }
  atomicAdd(&out[(b<<10) + t*4 + 0], a0);
  atomicAdd(&out[(b<<10) + t*4 + 1], a1);
  atomicAdd(&out[(b<<10) + t*4 + 2], a2);
  atomicAdd(&out[(b<<10) + t*4 + 3], a3);
}

// ---------------- launch ----------------
extern "C" void kernel_launch(void* const* d_in, const int* in_sizes, int n_in,
                              void* d_out, int out_size, void* d_ws, size_t ws_size,
                              hipStream_t stream)
{
  const float* hidden = (const float*)d_in[0];
  const int*   mask   = (const int*)d_in[1];
  const float* W0     = (const float*)d_in[2];
  const float* asrc0  = (const float*)d_in[3];
  const float* adst0  = (const float*)d_in[4];
  const float* wed0   = (const float*)d_in[5];
  const float* aed0   = (const float*)d_in[6];
  const float* bias0  = (const float*)d_in[7];
  const float* W1     = (const float*)d_in[8];
  const float* asrc1  = (const float*)d_in[9];
  const float* adst1  = (const float*)d_in[10];
  const float* wed1   = (const float*)d_in[11];
  const float* aed1   = (const float*)d_in[12];
  const float* bias1  = (const float*)d_in[13];
  const float* S1W    = (const float*)d_in[14];
  const float* S1b    = (const float*)d_in[15];
  const float* S2W    = (const float*)d_in[16];
  // S2b cancels in softmax.
  float* out = (float*)d_out;

  char* ws = (char*)d_ws;
  u16* hallc   = (u16*)(ws + 0);                  // 16384x1024 bf16 (32 MB)
  u16* partial = (u16*)(ws + 33554432);           // 16384x512 bf16 (16 MB)
  u16* gt2     = (u16*)(ws + 50331648);           // 16x128x1024 bf16 (4 MB)
  unsigned char* adj = (unsigned char*)(ws + 58720256); // 16 MB
  u16* gt   = (u16*)(ws + 75497472);              // 4 MB
  u16* w0t  = (u16*)(ws + 79691776);
  u16* w1t  = (u16*)(ws + 79888384);
  u16* s1t  = (u16*)(ws + 79921152);
  float* ald = (float*)(ws + 80969728);
  float* als = (float*)(ws + 81035264);
  float* scores = (float*)(ws + 81100800);
  float* als1   = (float*)(ws + 81166336);
  float* ald1   = (float*)(ws + 81231872);
  float* aeb    = (float*)(ws + 81297408);
  int*   cnt    = (int*)(ws + 81297920);
  int*   idxb   = (int*)(ws + 81298432);
  float* u0     = (float*)(ws + 81363968);
  float* v0     = (float*)(ws + 81367040);
  float* u1     = (float*)(ws + 81370112);
  float* v1     = (float*)(ws + 81370624);
  float* rn     = (float*)(ws + 81371136);

  pre_kernel<<<207, 1024, 0, stream>>>(out, scores, W0, w0t, W1, w1t, S1W, s1t,
      wed0, aed0, wed1, aed1, aeb, asrc0, adst0, asrc1, adst1,
      u0, v0, u1, v1, mask, cnt, idxb);

  hn_kernel<<<4096, 256, 0, stream>>>(hidden, cnt, idxb, u0, v0, aeb, hallc, rn, als, ald);

  // sim (symmetric band, rn-scaled) + proj0 + scorer K=768 bulk; 128x64 tiles
  mega_kernel<<<2432, 256, 0, stream>>>(hallc, w0t, s1t, rn, adj, gt, partial, cnt);

  // layer 0 (+ fused proj1 -> gt2, als1/ald1)
  gat_attn<1><<<1024, 256, 0, stream>>>(adj, ald, als, gt, bias0, cnt, hallc, 768,
        u1, v1, aeb + 1, als1, ald1, w1t, gt2);

  // layer 1
  gat_attn<0><<<1024, 256, 0, stream>>>(adj, ald1, als1, gt2, bias1, cnt, hallc, 896,
        nullptr, nullptr, nullptr, nullptr, nullptr, nullptr, nullptr);

  // scorer finisher: K=256 + partial + tanh + S2 dot
  scorer_fin<<<2048, 256, 0, stream>>>(hallc, s1t, partial, cnt, S1b, S2W, scores);

  pooled_kernel<<<dim3(16,16), 256, 0, stream>>>(hallc, scores, cnt, out);
}

// Round 13
// 115.043 us; speedup vs baseline: 1.0503x; 1.0503x over previous
//
#include <hip/hip_runtime.h>

typedef __attribute__((ext_vector_type(8))) short short8;
typedef __attribute__((ext_vector_type(4))) short s4v;
typedef __attribute__((ext_vector_type(4))) float f32x4;
typedef unsigned short u16;
typedef unsigned int u32;
typedef unsigned long long u64;

#define TAU_F 0.3f

__device__ __forceinline__ u16 f2bf(float f){
  u32 u = __float_as_uint(f);
  u32 r = u + 0x7FFFu + ((u >> 16) & 1u);
  return (u16)(r >> 16);
}
__device__ __forceinline__ float bf2f(u16 v){
  return __uint_as_float(((u32)v) << 16);
}
__device__ __forceinline__ float tanh_fast(float x){
  const float e = __expf(2.f * x);
  return 1.f - 2.f / (e + 1.f);
}

typedef __attribute__((address_space(1))) const u32 glb_u32;
typedef __attribute__((address_space(3))) u32 lds_u32;
__device__ __forceinline__ void async_lds16(const void* g, void* l){
  __builtin_amdgcn_global_load_lds((glb_u32*)g, (lds_u32*)l, 16, 0, 0);
}

// ---------------- merged preprocessing (one launch) --------------------------
__global__ __launch_bounds__(1024)
void pre_kernel(float* __restrict__ out, float* __restrict__ scores,
                const float* __restrict__ W0, u16* __restrict__ w0t,
                const float* __restrict__ W1, u16* __restrict__ w1t,
                const float* __restrict__ S1W, u16* __restrict__ s1t,
                const float* __restrict__ wed0, const float* __restrict__ aed0,
                const float* __restrict__ wed1, const float* __restrict__ aed1,
                float* __restrict__ aeb,
                const float* __restrict__ asrc0, const float* __restrict__ adst0,
                const float* __restrict__ asrc1, const float* __restrict__ adst1,
                float* __restrict__ u0, float* __restrict__ v0,
                float* __restrict__ u1, float* __restrict__ v1,
                const int* __restrict__ mask, int* __restrict__ cnt, int* __restrict__ idxb)
{
  __shared__ float lds[64*65];
  const int blk = blockIdx.x, t = threadIdx.x;

  auto tr_tile = [&](const float* in, u16* o, int K, int N, int kt, int ntile) {
    const int r = t >> 4, c0 = (t & 15) * 4;
    const int k0 = kt*64, n0 = ntile*64;
    const float4 v = *(const float4*)&in[(long)(k0 + r)*N + n0 + c0];
    lds[r*65 + c0 + 0] = v.x; lds[r*65 + c0 + 1] = v.y;
    lds[r*65 + c0 + 2] = v.z; lds[r*65 + c0 + 3] = v.w;
    __syncthreads();
    const u64 pk = (u64)f2bf(lds[(c0+0)*65 + r])
                 | ((u64)f2bf(lds[(c0+1)*65 + r]) << 16)
                 | ((u64)f2bf(lds[(c0+2)*65 + r]) << 32)
                 | ((u64)f2bf(lds[(c0+3)*65 + r]) << 48);
    *(u64*)&o[(long)(n0 + r)*K + k0 + c0] = pk;
  };

  if (blk < 16)  { out[blk*1024 + t] = 0.f; return; }
  if (blk < 32)  { scores[(blk-16)*1024 + t] = 0.f; return; }
  if (blk < 56)  { const int id = blk-32;  tr_tile(W0,  w0t, 768, 128, id >> 1, id & 1); return; }
  if (blk < 60)  { const int id = blk-56;  tr_tile(W1,  w1t, 128, 128, id >> 1, id & 1); return; }
  if (blk < 188) { const int id = blk-60;  tr_tile(S1W, s1t, 1024, 512, id >> 3, id & 7); return; }
  if (blk == 188) {
    if (t < 128) { lds[t] = wed0[t]*aed0[t]; lds[128+t] = wed1[t]*aed1[t]; }
    __syncthreads();
    for (int o = 64; o > 0; o >>= 1) { if (t < o) { lds[t] += lds[t+o]; lds[128+t] += lds[128+t+o]; } __syncthreads(); }
    if (t == 0) { aeb[0] = lds[0]; aeb[1] = lds[128]; }
    return;
  }
  if (blk == 189) {
    if (t < 768) {
      float su = 0.f, sv = 0.f;
      for (int c = 0; c < 128; c++) { const float w = W0[t*128 + c]; su += w*asrc0[c]; sv += w*adst0[c]; }
      u0[t] = su; v0[t] = sv;
    }
    return;
  }
  if (blk == 190) {
    if (t < 128) {
      float su = 0.f, sv = 0.f;
      for (int k = 0; k < 128; k++) { const float w = W1[k*128 + t]; su += w*asrc1[k]; sv += w*adst1[k]; }
      u1[t] = su; v1[t] = sv;
    }
    return;
  }
  { // compaction
    int* wtot = (int*)lds;
    int* woff = (int*)lds + 16;
    const int b = blk - 191;
    const int w = t >> 6, lane = t & 63;
    const int m = mask[(b << 10) + t];
    const u64 bal = __ballot(m != 0);
    const int pos = __popcll(bal & ((1ull << lane) - 1ull));
    if (lane == 0) wtot[w] = __popcll(bal);
    __syncthreads();
    if (t == 0) { int a = 0; for (int i = 0; i < 16; i++) { woff[i] = a; a += wtot[i]; } cnt[b] = a; }
    __syncthreads();
    if (m) idxb[(b << 10) + woff[w] + pos] = t;
  }
}

// ---- gather (no normalize store), rnorm, fused layer-0 als/ald --------------
__global__ __launch_bounds__(256)
void hn_kernel(const float* __restrict__ hidden, const int* __restrict__ cnt,
               const int* __restrict__ idx,
               const float* __restrict__ u0, const float* __restrict__ v0,
               const float* __restrict__ aeb,
               u16* __restrict__ hallc, float* __restrict__ rnp,
               float* __restrict__ als, float* __restrict__ ald)
{
  const int gr = blockIdx.x * 4 + (threadIdx.x >> 6);
  const int b = gr >> 10, c = gr & 1023;
  const int lane = threadIdx.x & 63;
  if (c >= cnt[b]) return;
  const int l = idx[gr];
  const float* h = hidden + (long)((b << 10) + l) * 768;
  float x[12]; float ss = 0.f, sa = 0.f, sd = 0.f;
#pragma unroll
  for (int k = 0; k < 12; k++) {
    x[k] = h[k*64 + lane];
    ss += x[k]*x[k];
    sa += x[k]*u0[k*64 + lane];
    sd += x[k]*v0[k*64 + lane];
  }
#pragma unroll
  for (int o = 32; o > 0; o >>= 1) {
    ss += __shfl_xor(ss, o, 64);
    sa += __shfl_xor(sa, o, 64);
    sd += __shfl_xor(sd, o, 64);
  }
  const float inv = 1.f / fmaxf(sqrtf(ss), 1e-8f);
  if (lane == 0) { als[gr] = sa; ald[gr] = sd + aeb[0]; rnp[gr] = inv; }
#pragma unroll
  for (int k = 0; k < 12; k++)
    hallc[(long)gr*1024 + k*64 + lane] = f2bf(x[k]);
}

// ------- mega GEMM launch: 64x64 tiles, BK=64, dbuf, XOR-swizzled ------------
// [0,2176): sim (XCD-pinned per batch; adj via rn scaling, mirror store)
// [2176,2688): proj0 (hallc @ w0t -> gt), row-panels pinned per XCD
// [2688,4736): scorer_p0 (hallc[:,0:768] @ s1t[:,0:768] -> bf16 partial)
__global__ __launch_bounds__(256)
void mega_kernel(const u16* __restrict__ hallc, const u16* __restrict__ w0t,
                 const u16* __restrict__ s1t, const float* __restrict__ rn,
                 unsigned char* __restrict__ adjp, u16* __restrict__ gtp,
                 u16* __restrict__ partial, const int* __restrict__ cnt)
{
  __shared__ u16 lA[2][64*64];
  __shared__ u16 lB[2][64*64];
  const int t = threadIdx.x, w = t >> 6, lane = t & 63;
  const int bid = blockIdx.x;
  int mode, bz = 0, i0, n0, lda, ldb, ti = 0, tj = 0, cb = 0;
  const u16 *Ab, *Bb;
  if (bid < 2176) {
    mode = 0;
    const int xcd = bid & 7, s = bid >> 3;
    const int hi = (s >= 136) ? 1 : 0;
    bz = xcd*2 + hi;
    int rem = s - hi*136, width = 16;
    while (rem >= width) { rem -= width; ti++; width--; }
    tj = ti + rem;
    i0 = ti*64; n0 = tj*64;
    cb = cnt[bz];
    if (i0 >= cb || n0 >= cb) return;
    Ab = hallc + (((long)bz << 10) << 10);
    Bb = Ab; lda = 1024; ldb = 1024;
  } else if (bid < 2688) {
    mode = 1;
    const int id = bid - 2176;
    i0 = (((id & 7) << 5) + ((id >> 3) & 31)) * 64;
    n0 = (id >> 8) * 64;
    if ((i0 & 1023) >= cnt[i0 >> 10]) return;
    Ab = hallc; lda = 1024; Bb = w0t; ldb = 768;
  } else {
    mode = 2;
    const int id = bid - 2688;
    i0 = (((id & 7) << 5) + ((id >> 3) & 31)) * 64;
    n0 = (id >> 8) * 64;
    if ((i0 & 1023) >= cnt[i0 >> 10]) return;
    Ab = hallc; lda = 1024; Bb = s1t; ldb = 1024;
  }
  const int wr = w >> 1, wc = w & 1;
  const int srow = t >> 3, scg = t & 7;
  const int sc0 = ((scg ^ (srow & 7)) << 3);
  const long arow0 = (long)(i0 + srow) * lda, arow1 = (long)(i0 + srow + 32) * lda;
  const long brow0 = (long)(n0 + srow) * ldb, brow1 = (long)(n0 + srow + 32) * ldb;
  const int rA = lane & 15, kg = lane >> 4;
  const int sw = rA & 7;
  const int off0 = ((kg ^ sw) << 3);
  const int off1 = (((4 + kg) ^ sw) << 3);
  const int rowA0 = (wr*32 + rA) * 64, rowA1 = (wr*32 + 16 + rA) * 64;
  const int rowB0 = (wc*32 + rA) * 64, rowB1 = (wc*32 + 16 + rA) * 64;
  f32x4 acc[2][2] = {};

  auto stage = [&](int buf, int kt) {
    async_lds16(Ab + arow0 + kt + sc0, &lA[buf][t*8]);
    async_lds16(Ab + arow1 + kt + sc0, &lA[buf][2048 + t*8]);
    async_lds16(Bb + brow0 + kt + sc0, &lB[buf][t*8]);
    async_lds16(Bb + brow1 + kt + sc0, &lB[buf][2048 + t*8]);
  };
  auto compute = [&](int buf) {
    short8 a00 = *(const short8*)&lA[buf][rowA0 + off0];
    short8 a01 = *(const short8*)&lA[buf][rowA0 + off1];
    short8 a10 = *(const short8*)&lA[buf][rowA1 + off0];
    short8 a11 = *(const short8*)&lA[buf][rowA1 + off1];
    short8 b00 = *(const short8*)&lB[buf][rowB0 + off0];
    short8 b01 = *(const short8*)&lB[buf][rowB0 + off1];
    short8 b10 = *(const short8*)&lB[buf][rowB1 + off0];
    short8 b11 = *(const short8*)&lB[buf][rowB1 + off1];
    acc[0][0] = __builtin_amdgcn_mfma_f32_16x16x32_bf16(a00, b00, acc[0][0], 0, 0, 0);
    acc[0][1] = __builtin_amdgcn_mfma_f32_16x16x32_bf16(a00, b10, acc[0][1], 0, 0, 0);
    acc[1][0] = __builtin_amdgcn_mfma_f32_16x16x32_bf16(a10, b00, acc[1][0], 0, 0, 0);
    acc[1][1] = __builtin_amdgcn_mfma_f32_16x16x32_bf16(a10, b10, acc[1][1], 0, 0, 0);
    acc[0][0] = __builtin_amdgcn_mfma_f32_16x16x32_bf16(a01, b01, acc[0][0], 0, 0, 0);
    acc[0][1] = __builtin_amdgcn_mfma_f32_16x16x32_bf16(a01, b11, acc[0][1], 0, 0, 0);
    acc[1][0] = __builtin_amdgcn_mfma_f32_16x16x32_bf16(a11, b01, acc[1][0], 0, 0, 0);
    acc[1][1] = __builtin_amdgcn_mfma_f32_16x16x32_bf16(a11, b11, acc[1][1], 0, 0, 0);
  };

  stage(0, 0);
  __syncthreads();
  int cur = 0;
  for (int kt = 1; kt < 12; kt++) {
    stage(cur ^ 1, kt << 6);
    compute(cur);
    __syncthreads();
    cur ^= 1;
  }
  compute(cur);

#pragma unroll
  for (int m = 0; m < 2; m++) {
    const int gi0 = i0 + wr*32 + m*16 + kg*4;
#pragma unroll
    for (int n = 0; n < 2; n++) {
      const int gj = n0 + wc*32 + n*16 + rA;
#pragma unroll
      for (int r = 0; r < 4; r++) {
        const int gi = gi0 + r;
        const float c = acc[m][n][r];
        if (mode == 0) {
          if (gi < cb && gj < cb) {
            const float sim = c * rn[(bz << 10) + gi] * rn[(bz << 10) + gj];
            const unsigned char e = (sim > TAU_F) ? 1 : 0;
            adjp[((long)bz << 20) + ((long)gi << 10) + gj] = e;
            if (ti != tj) adjp[((long)bz << 20) + ((long)gj << 10) + gi] = e;
          }
        } else if (mode == 1) {
          const int b = gi >> 10, l = gi & 1023;
          gtp[(((long)(b*128 + gj)) << 10) + l] = f2bf(c);
        } else {
          partial[(long)gi * 512 + gj] = f2bf(c);
        }
      }
    }
  }
}

// ------- scorer finisher: K=256 (h1|h2 slice) + partial + tanh + S2 dot ------
__global__ __launch_bounds__(256)
void scorer_fin(const u16* __restrict__ hallc, const u16* __restrict__ s1t,
                const u16* __restrict__ partial, const int* __restrict__ cnt,
                const float* __restrict__ s1b, const float* __restrict__ s2w,
                float* __restrict__ scoresp)
{
  __shared__ u16 lA[2][64*64];
  __shared__ u16 lB[2][64*64];
  __shared__ float sgrid[64];
  const int t = threadIdx.x, w = t >> 6, lane = t & 63;
  const int id = blockIdx.x;
  const int i0 = (((id & 7) << 5) + ((id >> 3) & 31)) * 64;
  const int n0 = (id >> 8) * 64;
  if ((i0 & 1023) >= cnt[i0 >> 10]) return;
  if (t < 64) sgrid[t] = 0.f;
  const int wr = w >> 1, wc = w & 1;
  const int srow = t >> 3, scg = t & 7;
  const int sc0 = ((scg ^ (srow & 7)) << 3);
  const long arow0 = (long)(i0 + srow) * 1024 + 768, arow1 = (long)(i0 + srow + 32) * 1024 + 768;
  const long brow0 = (long)(n0 + srow) * 1024 + 768, brow1 = (long)(n0 + srow + 32) * 1024 + 768;
  const int rA = lane & 15, kg = lane >> 4;
  const int sw = rA & 7;
  const int off0 = ((kg ^ sw) << 3);
  const int off1 = (((4 + kg) ^ sw) << 3);
  const int rowA0 = (wr*32 + rA) * 64, rowA1 = (wr*32 + 16 + rA) * 64;
  const int rowB0 = (wc*32 + rA) * 64, rowB1 = (wc*32 + 16 + rA) * 64;
  f32x4 acc[2][2] = {};

  auto stage = [&](int buf, int kt) {
    async_lds16(hallc + arow0 + kt + sc0, &lA[buf][t*8]);
    async_lds16(hallc + arow1 + kt + sc0, &lA[buf][2048 + t*8]);
    async_lds16(s1t + brow0 + kt + sc0, &lB[buf][t*8]);
    async_lds16(s1t + brow1 + kt + sc0, &lB[buf][2048 + t*8]);
  };
  auto compute = [&](int buf) {
    short8 a00 = *(const short8*)&lA[buf][rowA0 + off0];
    short8 a01 = *(const short8*)&lA[buf][rowA0 + off1];
    short8 a10 = *(const short8*)&lA[buf][rowA1 + off0];
    short8 a11 = *(const short8*)&lA[buf][rowA1 + off1];
    short8 b00 = *(const short8*)&lB[buf][rowB0 + off0];
    short8 b01 = *(const short8*)&lB[buf][rowB0 + off1];
    short8 b10 = *(const short8*)&lB[buf][rowB1 + off0];
    short8 b11 = *(const short8*)&lB[buf][rowB1 + off1];
    acc[0][0] = __builtin_amdgcn_mfma_f32_16x16x32_bf16(a00, b00, acc[0][0], 0, 0, 0);
    acc[0][1] = __builtin_amdgcn_mfma_f32_16x16x32_bf16(a00, b10, acc[0][1], 0, 0, 0);
    acc[1][0] = __builtin_amdgcn_mfma_f32_16x16x32_bf16(a10, b00, acc[1][0], 0, 0, 0);
    acc[1][1] = __builtin_amdgcn_mfma_f32_16x16x32_bf16(a10, b10, acc[1][1], 0, 0, 0);
    acc[0][0] = __builtin_amdgcn_mfma_f32_16x16x32_bf16(a01, b01, acc[0][0], 0, 0, 0);
    acc[0][1] = __builtin_amdgcn_mfma_f32_16x16x32_bf16(a01, b11, acc[0][1], 0, 0, 0);
    acc[1][0] = __builtin_amdgcn_mfma_f32_16x16x32_bf16(a11, b01, acc[1][0], 0, 0, 0);
    acc[1][1] = __builtin_amdgcn_mfma_f32_16x16x32_bf16(a11, b11, acc[1][1], 0, 0, 0);
  };

  stage(0, 0);
  __syncthreads();
  int cur = 0;
  for (int kt = 1; kt < 4; kt++) {
    stage(cur ^ 1, kt << 6);
    compute(cur);
    __syncthreads();
    cur ^= 1;
  }
  compute(cur);

#pragma unroll
  for (int m = 0; m < 2; m++)
#pragma unroll
    for (int r = 0; r < 4; r++) {
      const int gi = i0 + wr*32 + m*16 + kg*4 + r;
      float contrib = 0.f;
#pragma unroll
      for (int n = 0; n < 2; n++) {
        const int gj = n0 + wc*32 + n*16 + rA;
        const float p = acc[m][n][r] + bf2f(partial[(long)gi*512 + gj]) + s1b[gj];
        contrib += tanh_fast(p) * s2w[gj];
      }
#pragma unroll
      for (int off = 1; off < 16; off <<= 1) contrib += __shfl_xor(contrib, off, 64);
      if (rA == 0) atomicAdd(&sgrid[wr*32 + m*16 + kg*4 + r], contrib);
    }
  __syncthreads();
  if (t < 64) {
    const int gi = i0 + t;
    if ((gi & 1023) < cnt[gi >> 10]) atomicAdd(&scoresp[gi], sgrid[t]);
  }
}

// ---------------- fused GAT attention; FUSE=1 adds als1/ald1 + proj1->gt2 ----
template<int FUSE>
__global__ __launch_bounds__(256)
void gat_attn(const unsigned char* __restrict__ adj,
              const float* __restrict__ ald, const float* __restrict__ als,
              const u16* __restrict__ gT, const float* __restrict__ bias,
              const int* __restrict__ cnt,
              u16* __restrict__ hall, int hall_off,
              const float* __restrict__ u1, const float* __restrict__ v1,
              const float* __restrict__ aeb1,
              float* __restrict__ als_o, float* __restrict__ ald_o,
              const u16* __restrict__ w1t, u16* __restrict__ gt2)
{
  __shared__ float red[4][16][132];
  __shared__ float ssumw[4][16];
  __shared__ float alds[FUSE ? 16 : 1][17], aldd[FUSE ? 16 : 1][17];
  __shared__ u16 h1s[FUSE ? 16 : 1][136];
  const int t = threadIdx.x, w = t >> 6, lane = t & 63;
  const int o = blockIdx.x;
  const int xcd = o & 7, s = o >> 3;
  const int bz = xcd*2 + (s >> 6);
  const int i0 = (s & 63) * 16;
  const int cb = cnt[bz];
  if (i0 >= cb) return;
  const int rr = lane & 15, kg = lane >> 4;
  const int r0 = i0 + rr;
  const bool rvalid = r0 < cb;
  const float ald0 = ald[(bz << 10) + r0];
  const unsigned char* arow = adj + ((long)bz << 20) + ((long)r0 << 10);
  const float* als_b = als + (bz << 10);
  const u16* gTb = gT + ((long)bz << 17);
  float s0 = 0.f;
  f32x4 acc[8] = {};
  const int jbase = w * 256 + kg * 8;

  u64 aw[8];
#pragma unroll
  for (int it = 0; it < 8; it++) {
    const int jl = jbase + it*32;
    u64 a = 0;
    if (rvalid && jl < cb) {
      a = *(const u64*)(arow + jl);
      const int rem = cb - jl;
      if (rem < 8) a &= (1ull << (rem * 8)) - 1ull;
    }
    aw[it] = a;
  }

#pragma unroll
  for (int it = 0; it < 8; it++) {
    const u64 a0 = aw[it];
    if (__any(a0 != 0ull)) {
      const int jl = jbase + it*32;
      const float4 f0 = *(const float4*)(als_b + jl);
      const float4 f1 = *(const float4*)(als_b + jl + 4);
      const float sv[8] = {f0.x, f0.y, f0.z, f0.w, f1.x, f1.y, f1.z, f1.w};
      short8 pa;
#pragma unroll
      for (int e = 0; e < 8; e++) {
        float x = ald0 + sv[e];
        x = x > 0.f ? x : 0.2f * x;
        const float p = ((a0 >> (8*e)) & 255ull) ? __expf(x) : 0.f;
        s0 += p;
        pa[e] = (short)f2bf(p);
      }
#pragma unroll
      for (int nf = 0; nf < 8; nf++) {
        const short8 b = *(const short8*)&gTb[(long)(nf*16 + rr) * 1024 + jl];
        acc[nf] = __builtin_amdgcn_mfma_f32_16x16x32_bf16(pa, b, acc[nf], 0, 0, 0);
      }
    }
  }

  s0 += __shfl_xor(s0, 16, 64);
  s0 += __shfl_xor(s0, 32, 64);
  if (lane < 16) ssumw[w][lane] = s0;
#pragma unroll
  for (int nf = 0; nf < 8; nf++)
#pragma unroll
    for (int rg = 0; rg < 4; rg++)
      red[w][kg*4 + rg][nf*16 + rr] = acc[nf][rg];
  __syncthreads();

  const int r = t >> 4, c0 = (t & 15) * 8;
  const float sm = ssumw[0][r] + ssumw[1][r] + ssumw[2][r] + ssumw[3][r];
  const float inv = sm > 0.f ? 1.f / sm : 0.f;
  const long gi = ((long)bz << 10) + i0 + r;
  u16* orow = hall + gi * 1024 + hall_off;
  short8 hv;
  float pa_s = 0.f, pa_d = 0.f;
#pragma unroll
  for (int q = 0; q < 8; q++) {
    const int c = c0 + q;
    float v = (red[0][r][c] + red[1][r][c] + red[2][r][c] + red[3][r][c]) * inv + bias[c];
    v = v > 0.f ? v : 0.f;
    hv[q] = (short)f2bf(v);
    if (FUSE) { pa_s += v * u1[c]; pa_d += v * v1[c]; }
  }
  *(short8*)&orow[c0] = hv;
  if (FUSE) {
    *(short8*)&h1s[r][c0] = hv;
    alds[r][t & 15] = pa_s;
    aldd[r][t & 15] = pa_d;
    __syncthreads();
    if (t < 16) {
      float s2 = 0.f, d2 = 0.f;
#pragma unroll
      for (int j = 0; j < 16; j++) { s2 += alds[t][j]; d2 += aldd[t][j]; }
      als_o[(bz << 10) + i0 + t] = s2;
      ald_o[(bz << 10) + i0 + t] = d2 + aeb1[0];
    }
    // proj1: gt2 rows i0..i0+15 = h1s(16x128) @ W1; wave w covers cols [w*32,w*32+32)
    f32x4 pacc[2] = {};
    short8 paf[4];
#pragma unroll
    for (int ks = 0; ks < 4; ks++)
      paf[ks] = *(const short8*)&h1s[lane & 15][ks*32 + kg*8];
#pragma unroll
    for (int n = 0; n < 2; n++) {
      const int col = w*32 + n*16 + (lane & 15);
#pragma unroll
      for (int ks = 0; ks < 4; ks++) {
        const short8 pb = *(const short8*)&w1t[col*128 + ks*32 + kg*8];
        pacc[n] = __builtin_amdgcn_mfma_f32_16x16x32_bf16(paf[ks], pb, pacc[n], 0, 0, 0);
      }
    }
#pragma unroll
    for (int n = 0; n < 2; n++) {
      const int gj = w*32 + n*16 + (lane & 15);
#pragma unroll
      for (int rg = 0; rg < 4; rg++)
        gt2[(((long)(bz*128 + gj)) << 10) + i0 + kg*4 + rg] = f2bf(pacc[n][rg]);
    }
  }
}

// ---------------- pooled: softmax + weighted sum of bf16 hallc rows ----------
__global__ __launch_bounds__(256)
void pooled_kernel(const u16* __restrict__ hallc, const float* __restrict__ scores,
                   const int* __restrict__ cnt, float* __restrict__ out)
{
  __shared__ float tot[4];
  const int b = blockIdx.y, l0 = blockIdx.x * 64, t = threadIdx.x;
  const int cb = cnt[b];
  if (l0 >= cb) return;
  float part = 0.f;
#pragma unroll
  for (int q = 0; q < 4; q++) {
    const int l = q*256 + t;
    if (l < cb) part += __expf(scores[(b << 10) + l]);
  }
#pragma unroll
  for (int o = 32; o > 0; o >>= 1) part += __shfl_xor(part, o, 64);
  if ((t & 63) == 0) tot[t >> 6] = part;
  __syncthreads();
  const float inv = 1.f / fmaxf(tot[0] + tot[1] + tot[2] + tot[3], 1e-16f);

  const int lim = min(64, cb - l0);
  float a0 = 0.f, a1 = 0.f, a2 = 0.f, a3 = 0.f;
  for (int l = 0; l < lim; l++) {
    const int gl = (b << 10) + l0 + l;
    const float wv = __expf(scores[gl]) * inv;
    const s4v v = *(const s4v*)&hallc[(long)gl*1024 + t*4];
    a0 += wv * bf2f((u16)v[0]);
    a1 += wv * bf2f((u16)v[1]);
    a2 += wv * bf2f((u16)v[2]);
    a3 += wv * bf2f((u16)v[3]);
  }
  atomicAdd(&out[(b<<10) + t*4 + 0], a0);
  atomicAdd(&out[(b<<10) + t*4 + 1], a1);
  atomicAdd(&out[(b<<10) + t*4 + 2], a2);
  atomicAdd(&out[(b<<10) + t*4 + 3], a3);
}

// ---------------- launch ----------------
extern "C" void kernel_launch(void* const* d_in, const int* in_sizes, int n_in,
                              void* d_out, int out_size, void* d_ws, size_t ws_size,
                              hipStream_t stream)
{
  const float* hidden = (const float*)d_in[0];
  const int*   mask   = (const int*)d_in[1];
  const float* W0     = (const float*)d_in[2];
  const float* asrc0  = (const float*)d_in[3];
  const float* adst0  = (const float*)d_in[4];
  const float* wed0   = (const float*)d_in[5];
  const float* aed0   = (const float*)d_in[6];
  const float* bias0  = (const float*)d_in[7];
  const float* W1     = (const float*)d_in[8];
  const float* asrc1  = (const float*)d_in[9];
  const float* adst1  = (const float*)d_in[10];
  const float* wed1   = (const float*)d_in[11];
  const float* aed1   = (const float*)d_in[12];
  const float* bias1  = (const float*)d_in[13];
  const float* S1W    = (const float*)d_in[14];
  const float* S1b    = (const float*)d_in[15];
  const float* S2W    = (const float*)d_in[16];
  // S2b cancels in softmax.
  float* out = (float*)d_out;

  char* ws = (char*)d_ws;
  u16* hallc   = (u16*)(ws + 0);                  // 16384x1024 bf16 (32 MB)
  u16* partial = (u16*)(ws + 33554432);           // 16384x512 bf16 (16 MB)
  u16* gt2     = (u16*)(ws + 50331648);           // 16x128x1024 bf16 (4 MB)
  unsigned char* adj = (unsigned char*)(ws + 58720256); // 16 MB
  u16* gt   = (u16*)(ws + 75497472);              // 4 MB
  u16* w0t  = (u16*)(ws + 79691776);
  u16* w1t  = (u16*)(ws + 79888384);
  u16* s1t  = (u16*)(ws + 79921152);
  float* ald = (float*)(ws + 80969728);
  float* als = (float*)(ws + 81035264);
  float* scores = (float*)(ws + 81100800);
  float* als1   = (float*)(ws + 81166336);
  float* ald1   = (float*)(ws + 81231872);
  float* aeb    = (float*)(ws + 81297408);
  int*   cnt    = (int*)(ws + 81297920);
  int*   idxb   = (int*)(ws + 81298432);
  float* u0     = (float*)(ws + 81363968);
  float* v0     = (float*)(ws + 81367040);
  float* u1     = (float*)(ws + 81370112);
  float* v1     = (float*)(ws + 81370624);
  float* rn     = (float*)(ws + 81371136);

  pre_kernel<<<207, 1024, 0, stream>>>(out, scores, W0, w0t, W1, w1t, S1W, s1t,
      wed0, aed0, wed1, aed1, aeb, asrc0, adst0, asrc1, adst1,
      u0, v0, u1, v1, mask, cnt, idxb);

  hn_kernel<<<4096, 256, 0, stream>>>(hidden, cnt, idxb, u0, v0, aeb, hallc, rn, als, ald);

  // sim (symmetric triangle, rn-scaled) + proj0 + scorer K=768 bulk; 64x64 tiles
  mega_kernel<<<4736, 256, 0, stream>>>(hallc, w0t, s1t, rn, adj, gt, partial, cnt);

  // layer 0 (+ fused proj1 -> gt2, als1/ald1)
  gat_attn<1><<<1024, 256, 0, stream>>>(adj, ald, als, gt, bias0, cnt, hallc, 768,
        u1, v1, aeb + 1, als1, ald1, w1t, gt2);

  // layer 1
  gat_attn<0><<<1024, 256, 0, stream>>>(adj, ald1, als1, gt2, bias1, cnt, hallc, 896,
        nullptr, nullptr, nullptr, nullptr, nullptr, nullptr, nullptr);

  // scorer finisher: K=256 + partial + tanh + S2 dot
  scorer_fin<<<2048, 256, 0, stream>>>(hallc, s1t, partial, cnt, S1b, S2W, scores);

  pooled_kernel<<<dim3(16,16), 256, 0, stream>>>(hallc, scores, cnt, out);
}

// Round 14
// 97.790 us; speedup vs baseline: 1.2356x; 1.1764x over previous
//
#include <hip/hip_runtime.h>

typedef __attribute__((ext_vector_type(8))) short short8;
typedef __attribute__((ext_vector_type(4))) short s4v;
typedef __attribute__((ext_vector_type(4))) float f32x4;
typedef unsigned short u16;
typedef unsigned int u32;
typedef unsigned long long u64;

#define TAU_F 0.3f

__device__ __forceinline__ u16 f2bf(float f){
  u32 u = __float_as_uint(f);
  u32 r = u + 0x7FFFu + ((u >> 16) & 1u);
  return (u16)(r >> 16);
}
__device__ __forceinline__ float bf2f(u16 v){
  return __uint_as_float(((u32)v) << 16);
}
__device__ __forceinline__ float tanh_fast(float x){
  const float e = __expf(2.f * x);
  return 1.f - 2.f / (e + 1.f);
}

typedef __attribute__((address_space(1))) const u32 glb_u32;
typedef __attribute__((address_space(3))) u32 lds_u32;
__device__ __forceinline__ void async_lds16(const void* g, void* l){
  __builtin_amdgcn_global_load_lds((glb_u32*)g, (lds_u32*)l, 16, 0, 0);
}

// ---------------- merged preprocessing (one launch) --------------------------
// [0,16) zero out | [16,32) zero scores | [32,56) W0^T | [56,60) W1^T
// [60,188) S1W^T | 188 ae | [189,195) u0/v0 (6 blocks, coalesced) | 195 u1/v1
// [196,212) compaction
__global__ __launch_bounds__(1024)
void pre_kernel(float* __restrict__ out, float* __restrict__ scores,
                const float* __restrict__ W0, u16* __restrict__ w0t,
                const float* __restrict__ W1, u16* __restrict__ w1t,
                const float* __restrict__ S1W, u16* __restrict__ s1t,
                const float* __restrict__ wed0, const float* __restrict__ aed0,
                const float* __restrict__ wed1, const float* __restrict__ aed1,
                float* __restrict__ aeb,
                const float* __restrict__ asrc0, const float* __restrict__ adst0,
                const float* __restrict__ asrc1, const float* __restrict__ adst1,
                float* __restrict__ u0, float* __restrict__ v0,
                float* __restrict__ u1, float* __restrict__ v1,
                const int* __restrict__ mask, int* __restrict__ cnt, int* __restrict__ idxb)
{
  __shared__ float lds[64*65];
  const int blk = blockIdx.x, t = threadIdx.x;

  auto tr_tile = [&](const float* in, u16* o, int K, int N, int kt, int ntile) {
    const int r = t >> 4, c0 = (t & 15) * 4;
    const int k0 = kt*64, n0 = ntile*64;
    const float4 v = *(const float4*)&in[(long)(k0 + r)*N + n0 + c0];
    lds[r*65 + c0 + 0] = v.x; lds[r*65 + c0 + 1] = v.y;
    lds[r*65 + c0 + 2] = v.z; lds[r*65 + c0 + 3] = v.w;
    __syncthreads();
    const u64 pk = (u64)f2bf(lds[(c0+0)*65 + r])
                 | ((u64)f2bf(lds[(c0+1)*65 + r]) << 16)
                 | ((u64)f2bf(lds[(c0+2)*65 + r]) << 32)
                 | ((u64)f2bf(lds[(c0+3)*65 + r]) << 48);
    *(u64*)&o[(long)(n0 + r)*K + k0 + c0] = pk;
  };

  if (blk < 16)  { out[blk*1024 + t] = 0.f; return; }
  if (blk < 32)  { scores[(blk-16)*1024 + t] = 0.f; return; }
  if (blk < 56)  { const int id = blk-32;  tr_tile(W0,  w0t, 768, 128, id >> 1, id & 1); return; }
  if (blk < 60)  { const int id = blk-56;  tr_tile(W1,  w1t, 128, 128, id >> 1, id & 1); return; }
  if (blk < 188) { const int id = blk-60;  tr_tile(S1W, s1t, 1024, 512, id >> 3, id & 7); return; }
  if (blk == 188) {
    if (t < 128) { lds[t] = wed0[t]*aed0[t]; lds[128+t] = wed1[t]*aed1[t]; }
    __syncthreads();
    for (int o = 64; o > 0; o >>= 1) { if (t < o) { lds[t] += lds[t+o]; lds[128+t] += lds[128+t+o]; } __syncthreads(); }
    if (t == 0) { aeb[0] = lds[0]; aeb[1] = lds[128]; }
    return;
  }
  if (blk < 195) {                                   // u0/v0: 6 blocks x 128 rows
    const int q = blk - 189;
    const int row = q*128 + (t >> 3);
    const int c0 = (t & 7) * 16;
    float su = 0.f, sv = 0.f;
#pragma unroll
    for (int i = 0; i < 16; i += 4) {
      const float4 wv = *(const float4*)&W0[row*128 + c0 + i];
      const float4 sa = *(const float4*)&asrc0[c0 + i];
      const float4 da = *(const float4*)&adst0[c0 + i];
      su += wv.x*sa.x + wv.y*sa.y + wv.z*sa.z + wv.w*sa.w;
      sv += wv.x*da.x + wv.y*da.y + wv.z*da.z + wv.w*da.w;
    }
    su += __shfl_xor(su, 1, 64); su += __shfl_xor(su, 2, 64); su += __shfl_xor(su, 4, 64);
    sv += __shfl_xor(sv, 1, 64); sv += __shfl_xor(sv, 2, 64); sv += __shfl_xor(sv, 4, 64);
    if ((t & 7) == 0) { u0[row] = su; v0[row] = sv; }
    return;
  }
  if (blk == 195) {
    if (t < 128) {
      float su = 0.f, sv = 0.f;
      for (int k = 0; k < 128; k++) { const float w = W1[k*128 + t]; su += w*asrc1[k]; sv += w*adst1[k]; }
      u1[t] = su; v1[t] = sv;
    }
    return;
  }
  { // compaction
    int* wtot = (int*)lds;
    int* woff = (int*)lds + 16;
    const int b = blk - 196;
    const int w = t >> 6, lane = t & 63;
    const int m = mask[(b << 10) + t];
    const u64 bal = __ballot(m != 0);
    const int pos = __popcll(bal & ((1ull << lane) - 1ull));
    if (lane == 0) wtot[w] = __popcll(bal);
    __syncthreads();
    if (t == 0) { int a = 0; for (int i = 0; i < 16; i++) { woff[i] = a; a += wtot[i]; } cnt[b] = a; }
    __syncthreads();
    if (m) idxb[(b << 10) + woff[w] + pos] = t;
  }
}

// ---- gather (no normalize store), rnorm, fused layer-0 als/ald --------------
__global__ __launch_bounds__(256)
void hn_kernel(const float* __restrict__ hidden, const int* __restrict__ cnt,
               const int* __restrict__ idx,
               const float* __restrict__ u0, const float* __restrict__ v0,
               const float* __restrict__ aeb,
               u16* __restrict__ hallc, float* __restrict__ rnp,
               float* __restrict__ als, float* __restrict__ ald)
{
  const int gr = blockIdx.x * 4 + (threadIdx.x >> 6);
  const int b = gr >> 10, c = gr & 1023;
  const int lane = threadIdx.x & 63;
  if (c >= cnt[b]) return;
  const int l = idx[gr];
  const float* h = hidden + (long)((b << 10) + l) * 768;
  float x[12]; float ss = 0.f, sa = 0.f, sd = 0.f;
#pragma unroll
  for (int k = 0; k < 12; k++) {
    x[k] = h[k*64 + lane];
    ss += x[k]*x[k];
    sa += x[k]*u0[k*64 + lane];
    sd += x[k]*v0[k*64 + lane];
  }
#pragma unroll
  for (int o = 32; o > 0; o >>= 1) {
    ss += __shfl_xor(ss, o, 64);
    sa += __shfl_xor(sa, o, 64);
    sd += __shfl_xor(sd, o, 64);
  }
  const float inv = 1.f / fmaxf(sqrtf(ss), 1e-8f);
  if (lane == 0) { als[gr] = sa; ald[gr] = sd + aeb[0]; rnp[gr] = inv; }
#pragma unroll
  for (int k = 0; k < 12; k++)
    hallc[(long)gr*1024 + k*64 + lane] = f2bf(x[k]);
}

// ------- mega GEMM launch: 64x64 tiles, BK=64, depth-2 counted-vmcnt pipeline
// [0,2176): sim (XCD-pinned per batch; adj via rn scaling, mirror store)
// [2176,2688): proj0 (hallc @ w0t -> gt)
// [2688,4736): scorer_p0 (hallc[:,0:768] @ s1t[:,0:768] -> bf16 partial)
__global__ __launch_bounds__(256)
void mega_kernel(const u16* __restrict__ hallc, const u16* __restrict__ w0t,
                 const u16* __restrict__ s1t, const float* __restrict__ rn,
                 unsigned char* __restrict__ adjp, u16* __restrict__ gtp,
                 u16* __restrict__ partial, const int* __restrict__ cnt)
{
  __shared__ u16 lA[2][64*64];
  __shared__ u16 lB[2][64*64];
  const int t = threadIdx.x, w = t >> 6, lane = t & 63;
  const int bid = blockIdx.x;
  int mode, bz = 0, i0, n0, lda, ldb, ti = 0, tj = 0, cb = 0;
  const u16 *Ab, *Bb;
  if (bid < 2176) {
    mode = 0;
    const int xcd = bid & 7, s = bid >> 3;
    const int hi = (s >= 136) ? 1 : 0;
    bz = xcd*2 + hi;
    int rem = s - hi*136, width = 16;
    while (rem >= width) { rem -= width; ti++; width--; }
    tj = ti + rem;
    i0 = ti*64; n0 = tj*64;
    cb = cnt[bz];
    if (i0 >= cb || n0 >= cb) return;
    Ab = hallc + (((long)bz << 10) << 10);
    Bb = Ab; lda = 1024; ldb = 1024;
  } else if (bid < 2688) {
    mode = 1;
    const int id = bid - 2176;
    i0 = (((id & 7) << 5) + ((id >> 3) & 31)) * 64;
    n0 = (id >> 8) * 64;
    if ((i0 & 1023) >= cnt[i0 >> 10]) return;
    Ab = hallc; lda = 1024; Bb = w0t; ldb = 768;
  } else {
    mode = 2;
    const int id = bid - 2688;
    i0 = (((id & 7) << 5) + ((id >> 3) & 31)) * 64;
    n0 = (id >> 8) * 64;
    if ((i0 & 1023) >= cnt[i0 >> 10]) return;
    Ab = hallc; lda = 1024; Bb = s1t; ldb = 1024;
  }
  const int wr = w >> 1, wc = w & 1;
  const int srow = t >> 3, scg = t & 7;
  const int sc0 = ((scg ^ (srow & 7)) << 3);
  const long arow0 = (long)(i0 + srow) * lda, arow1 = (long)(i0 + srow + 32) * lda;
  const long brow0 = (long)(n0 + srow) * ldb, brow1 = (long)(n0 + srow + 32) * ldb;
  const int rA = lane & 15, kg = lane >> 4;
  const int sw = rA & 7;
  const int off0 = ((kg ^ sw) << 3);
  const int off1 = (((4 + kg) ^ sw) << 3);
  const int rowA0 = (wr*32 + rA) * 64, rowA1 = (wr*32 + 16 + rA) * 64;
  const int rowB0 = (wc*32 + rA) * 64, rowB1 = (wc*32 + 16 + rA) * 64;
  f32x4 acc[2][2] = {};

  auto stage = [&](int buf, int kt) {
    async_lds16(Ab + arow0 + kt + sc0, &lA[buf][t*8]);
    async_lds16(Ab + arow1 + kt + sc0, &lA[buf][2048 + t*8]);
    async_lds16(Bb + brow0 + kt + sc0, &lB[buf][t*8]);
    async_lds16(Bb + brow1 + kt + sc0, &lB[buf][2048 + t*8]);
  };
  auto compute = [&](int buf) {
    short8 a00 = *(const short8*)&lA[buf][rowA0 + off0];
    short8 a01 = *(const short8*)&lA[buf][rowA0 + off1];
    short8 a10 = *(const short8*)&lA[buf][rowA1 + off0];
    short8 a11 = *(const short8*)&lA[buf][rowA1 + off1];
    short8 b00 = *(const short8*)&lB[buf][rowB0 + off0];
    short8 b01 = *(const short8*)&lB[buf][rowB0 + off1];
    short8 b10 = *(const short8*)&lB[buf][rowB1 + off0];
    short8 b11 = *(const short8*)&lB[buf][rowB1 + off1];
    acc[0][0] = __builtin_amdgcn_mfma_f32_16x16x32_bf16(a00, b00, acc[0][0], 0, 0, 0);
    acc[0][1] = __builtin_amdgcn_mfma_f32_16x16x32_bf16(a00, b10, acc[0][1], 0, 0, 0);
    acc[1][0] = __builtin_amdgcn_mfma_f32_16x16x32_bf16(a10, b00, acc[1][0], 0, 0, 0);
    acc[1][1] = __builtin_amdgcn_mfma_f32_16x16x32_bf16(a10, b10, acc[1][1], 0, 0, 0);
    acc[0][0] = __builtin_amdgcn_mfma_f32_16x16x32_bf16(a01, b01, acc[0][0], 0, 0, 0);
    acc[0][1] = __builtin_amdgcn_mfma_f32_16x16x32_bf16(a01, b11, acc[0][1], 0, 0, 0);
    acc[1][0] = __builtin_amdgcn_mfma_f32_16x16x32_bf16(a11, b01, acc[1][0], 0, 0, 0);
    acc[1][1] = __builtin_amdgcn_mfma_f32_16x16x32_bf16(a11, b11, acc[1][1], 0, 0, 0);
  };

  // depth-2 pipeline: both buffers staged ahead; counted vmcnt keeps the
  // next tile's 4 loads in flight across the barrier (never drain to 0
  // in steady state).
  stage(0, 0);
  stage(1, 64);
  int cur = 0;
  for (int kt = 0; kt < 10; kt++) {
    asm volatile("s_waitcnt vmcnt(4)" ::: "memory");
    __builtin_amdgcn_s_barrier();
    compute(cur);
    __builtin_amdgcn_s_barrier();
    stage(cur, (kt + 2) << 6);
    cur ^= 1;
  }
  asm volatile("s_waitcnt vmcnt(4)" ::: "memory");
  __builtin_amdgcn_s_barrier();
  compute(cur);
  asm volatile("s_waitcnt vmcnt(0)" ::: "memory");
  __builtin_amdgcn_s_barrier();
  compute(cur ^ 1);

#pragma unroll
  for (int m = 0; m < 2; m++) {
    const int gi0 = i0 + wr*32 + m*16 + kg*4;
#pragma unroll
    for (int n = 0; n < 2; n++) {
      const int gj = n0 + wc*32 + n*16 + rA;
#pragma unroll
      for (int r = 0; r < 4; r++) {
        const int gi = gi0 + r;
        const float c = acc[m][n][r];
        if (mode == 0) {
          if (gi < cb && gj < cb) {
            const float sim = c * rn[(bz << 10) + gi] * rn[(bz << 10) + gj];
            const unsigned char e = (sim > TAU_F) ? 1 : 0;
            adjp[((long)bz << 20) + ((long)gi << 10) + gj] = e;
            if (ti != tj) adjp[((long)bz << 20) + ((long)gj << 10) + gi] = e;
          }
        } else if (mode == 1) {
          const int b = gi >> 10, l = gi & 1023;
          gtp[(((long)(b*128 + gj)) << 10) + l] = f2bf(c);
        } else {
          partial[(long)gi * 512 + gj] = f2bf(c);
        }
      }
    }
  }
}

// ------- scorer finisher: K=256 (h1|h2 slice) + partial + tanh + S2 dot ------
__global__ __launch_bounds__(256)
void scorer_fin(const u16* __restrict__ hallc, const u16* __restrict__ s1t,
                const u16* __restrict__ partial, const int* __restrict__ cnt,
                const float* __restrict__ s1b, const float* __restrict__ s2w,
                float* __restrict__ scoresp)
{
  __shared__ u16 lA[2][64*64];
  __shared__ u16 lB[2][64*64];
  __shared__ float sgrid[64];
  const int t = threadIdx.x, w = t >> 6, lane = t & 63;
  const int id = blockIdx.x;
  const int i0 = (((id & 7) << 5) + ((id >> 3) & 31)) * 64;
  const int n0 = (id >> 8) * 64;
  if ((i0 & 1023) >= cnt[i0 >> 10]) return;
  if (t < 64) sgrid[t] = 0.f;
  const int wr = w >> 1, wc = w & 1;
  const int srow = t >> 3, scg = t & 7;
  const int sc0 = ((scg ^ (srow & 7)) << 3);
  const long arow0 = (long)(i0 + srow) * 1024 + 768, arow1 = (long)(i0 + srow + 32) * 1024 + 768;
  const long brow0 = (long)(n0 + srow) * 1024 + 768, brow1 = (long)(n0 + srow + 32) * 1024 + 768;
  const int rA = lane & 15, kg = lane >> 4;
  const int sw = rA & 7;
  const int off0 = ((kg ^ sw) << 3);
  const int off1 = (((4 + kg) ^ sw) << 3);
  const int rowA0 = (wr*32 + rA) * 64, rowA1 = (wr*32 + 16 + rA) * 64;
  const int rowB0 = (wc*32 + rA) * 64, rowB1 = (wc*32 + 16 + rA) * 64;
  f32x4 acc[2][2] = {};

  auto stage = [&](int buf, int kt) {
    async_lds16(hallc + arow0 + kt + sc0, &lA[buf][t*8]);
    async_lds16(hallc + arow1 + kt + sc0, &lA[buf][2048 + t*8]);
    async_lds16(s1t + brow0 + kt + sc0, &lB[buf][t*8]);
    async_lds16(s1t + brow1 + kt + sc0, &lB[buf][2048 + t*8]);
  };
  auto compute = [&](int buf) {
    short8 a00 = *(const short8*)&lA[buf][rowA0 + off0];
    short8 a01 = *(const short8*)&lA[buf][rowA0 + off1];
    short8 a10 = *(const short8*)&lA[buf][rowA1 + off0];
    short8 a11 = *(const short8*)&lA[buf][rowA1 + off1];
    short8 b00 = *(const short8*)&lB[buf][rowB0 + off0];
    short8 b01 = *(const short8*)&lB[buf][rowB0 + off1];
    short8 b10 = *(const short8*)&lB[buf][rowB1 + off0];
    short8 b11 = *(const short8*)&lB[buf][rowB1 + off1];
    acc[0][0] = __builtin_amdgcn_mfma_f32_16x16x32_bf16(a00, b00, acc[0][0], 0, 0, 0);
    acc[0][1] = __builtin_amdgcn_mfma_f32_16x16x32_bf16(a00, b10, acc[0][1], 0, 0, 0);
    acc[1][0] = __builtin_amdgcn_mfma_f32_16x16x32_bf16(a10, b00, acc[1][0], 0, 0, 0);
    acc[1][1] = __builtin_amdgcn_mfma_f32_16x16x32_bf16(a10, b10, acc[1][1], 0, 0, 0);
    acc[0][0] = __builtin_amdgcn_mfma_f32_16x16x32_bf16(a01, b01, acc[0][0], 0, 0, 0);
    acc[0][1] = __builtin_amdgcn_mfma_f32_16x16x32_bf16(a01, b11, acc[0][1], 0, 0, 0);
    acc[1][0] = __builtin_amdgcn_mfma_f32_16x16x32_bf16(a11, b01, acc[1][0], 0, 0, 0);
    acc[1][1] = __builtin_amdgcn_mfma_f32_16x16x32_bf16(a11, b11, acc[1][1], 0, 0, 0);
  };

  stage(0, 0);
  __syncthreads();
  int cur = 0;
  for (int kt = 1; kt < 4; kt++) {
    stage(cur ^ 1, kt << 6);
    compute(cur);
    __syncthreads();
    cur ^= 1;
  }
  compute(cur);

#pragma unroll
  for (int m = 0; m < 2; m++)
#pragma unroll
    for (int r = 0; r < 4; r++) {
      const int gi = i0 + wr*32 + m*16 + kg*4 + r;
      float contrib = 0.f;
#pragma unroll
      for (int n = 0; n < 2; n++) {
        const int gj = n0 + wc*32 + n*16 + rA;
        const float p = acc[m][n][r] + bf2f(partial[(long)gi*512 + gj]) + s1b[gj];
        contrib += tanh_fast(p) * s2w[gj];
      }
#pragma unroll
      for (int off = 1; off < 16; off <<= 1) contrib += __shfl_xor(contrib, off, 64);
      if (rA == 0) atomicAdd(&sgrid[wr*32 + m*16 + kg*4 + r], contrib);
    }
  __syncthreads();
  if (t < 64) {
    const int gi = i0 + t;
    if ((gi & 1023) < cnt[gi >> 10]) atomicAdd(&scoresp[gi], sgrid[t]);
  }
}

// ---------------- fused GAT attention; FUSE=1 adds als1/ald1 + proj1->gt2 ----
template<int FUSE>
__global__ __launch_bounds__(256)
void gat_attn(const unsigned char* __restrict__ adj,
              const float* __restrict__ ald, const float* __restrict__ als,
              const u16* __restrict__ gT, const float* __restrict__ bias,
              const int* __restrict__ cnt,
              u16* __restrict__ hall, int hall_off,
              const float* __restrict__ u1, const float* __restrict__ v1,
              const float* __restrict__ aeb1,
              float* __restrict__ als_o, float* __restrict__ ald_o,
              const u16* __restrict__ w1t, u16* __restrict__ gt2)
{
  __shared__ float red[4][16][132];
  __shared__ float ssumw[4][16];
  __shared__ float alds[FUSE ? 16 : 1][17], aldd[FUSE ? 16 : 1][17];
  __shared__ u16 h1s[FUSE ? 16 : 1][136];
  const int t = threadIdx.x, w = t >> 6, lane = t & 63;
  const int o = blockIdx.x;
  const int xcd = o & 7, s = o >> 3;
  const int bz = xcd*2 + (s >> 6);
  const int i0 = (s & 63) * 16;
  const int cb = cnt[bz];
  if (i0 >= cb) return;
  const int rr = lane & 15, kg = lane >> 4;
  const int r0 = i0 + rr;
  const bool rvalid = r0 < cb;
  const float ald0 = ald[(bz << 10) + r0];
  const unsigned char* arow = adj + ((long)bz << 20) + ((long)r0 << 10);
  const float* als_b = als + (bz << 10);
  const u16* gTb = gT + ((long)bz << 17);
  float s0 = 0.f;
  f32x4 acc[8] = {};
  const int jbase = w * 256 + kg * 8;

  u64 aw[8];
#pragma unroll
  for (int it = 0; it < 8; it++) {
    const int jl = jbase + it*32;
    u64 a = 0;
    if (rvalid && jl < cb) {
      a = *(const u64*)(arow + jl);
      const int rem = cb - jl;
      if (rem < 8) a &= (1ull << (rem * 8)) - 1ull;
    }
    aw[it] = a;
  }

#pragma unroll
  for (int it = 0; it < 8; it++) {
    const u64 a0 = aw[it];
    if (__any(a0 != 0ull)) {
      const int jl = jbase + it*32;
      const float4 f0 = *(const float4*)(als_b + jl);
      const float4 f1 = *(const float4*)(als_b + jl + 4);
      const float sv[8] = {f0.x, f0.y, f0.z, f0.w, f1.x, f1.y, f1.z, f1.w};
      short8 pa;
#pragma unroll
      for (int e = 0; e < 8; e++) {
        float x = ald0 + sv[e];
        x = x > 0.f ? x : 0.2f * x;
        const float p = ((a0 >> (8*e)) & 255ull) ? __expf(x) : 0.f;
        s0 += p;
        pa[e] = (short)f2bf(p);
      }
#pragma unroll
      for (int nf = 0; nf < 8; nf++) {
        const short8 b = *(const short8*)&gTb[(long)(nf*16 + rr) * 1024 + jl];
        acc[nf] = __builtin_amdgcn_mfma_f32_16x16x32_bf16(pa, b, acc[nf], 0, 0, 0);
      }
    }
  }

  s0 += __shfl_xor(s0, 16, 64);
  s0 += __shfl_xor(s0, 32, 64);
  if (lane < 16) ssumw[w][lane] = s0;
#pragma unroll
  for (int nf = 0; nf < 8; nf++)
#pragma unroll
    for (int rg = 0; rg < 4; rg++)
      red[w][kg*4 + rg][nf*16 + rr] = acc[nf][rg];
  __syncthreads();

  const int r = t >> 4, c0 = (t & 15) * 8;
  const float sm = ssumw[0][r] + ssumw[1][r] + ssumw[2][r] + ssumw[3][r];
  const float inv = sm > 0.f ? 1.f / sm : 0.f;
  const long gi = ((long)bz << 10) + i0 + r;
  u16* orow = hall + gi * 1024 + hall_off;
  short8 hv;
  float pa_s = 0.f, pa_d = 0.f;
#pragma unroll
  for (int q = 0; q < 8; q++) {
    const int c = c0 + q;
    float v = (red[0][r][c] + red[1][r][c] + red[2][r][c] + red[3][r][c]) * inv + bias[c];
    v = v > 0.f ? v : 0.f;
    hv[q] = (short)f2bf(v);
    if (FUSE) { pa_s += v * u1[c]; pa_d += v * v1[c]; }
  }
  *(short8*)&orow[c0] = hv;
  if (FUSE) {
    *(short8*)&h1s[r][c0] = hv;
    alds[r][t & 15] = pa_s;
    aldd[r][t & 15] = pa_d;
    __syncthreads();
    if (t < 16) {
      float s2 = 0.f, d2 = 0.f;
#pragma unroll
      for (int j = 0; j < 16; j++) { s2 += alds[t][j]; d2 += aldd[t][j]; }
      als_o[(bz << 10) + i0 + t] = s2;
      ald_o[(bz << 10) + i0 + t] = d2 + aeb1[0];
    }
    // proj1: gt2 rows i0..i0+15 = h1s(16x128) @ W1; wave w covers cols [w*32,w*32+32)
    f32x4 pacc[2] = {};
    short8 paf[4];
#pragma unroll
    for (int ks = 0; ks < 4; ks++)
      paf[ks] = *(const short8*)&h1s[lane & 15][ks*32 + kg*8];
#pragma unroll
    for (int n = 0; n < 2; n++) {
      const int col = w*32 + n*16 + (lane & 15);
#pragma unroll
      for (int ks = 0; ks < 4; ks++) {
        const short8 pb = *(const short8*)&w1t[col*128 + ks*32 + kg*8];
        pacc[n] = __builtin_amdgcn_mfma_f32_16x16x32_bf16(paf[ks], pb, pacc[n], 0, 0, 0);
      }
    }
#pragma unroll
    for (int n = 0; n < 2; n++) {
      const int gj = w*32 + n*16 + (lane & 15);
#pragma unroll
      for (int rg = 0; rg < 4; rg++)
        gt2[(((long)(bz*128 + gj)) << 10) + i0 + kg*4 + rg] = f2bf(pacc[n][rg]);
    }
  }
}

// ---------------- pooled: softmax + weighted sum of bf16 hallc rows ----------
__global__ __launch_bounds__(256)
void pooled_kernel(const u16* __restrict__ hallc, const float* __restrict__ scores,
                   const int* __restrict__ cnt, float* __restrict__ out)
{
  __shared__ float tot[4];
  const int b = blockIdx.y, l0 = blockIdx.x * 16, t = threadIdx.x;
  const int cb = cnt[b];
  if (l0 >= cb) return;
  float part = 0.f;
#pragma unroll
  for (int q = 0; q < 4; q++) {
    const int l = q*256 + t;
    if (l < cb) part += __expf(scores[(b << 10) + l]);
  }
#pragma unroll
  for (int o = 32; o > 0; o >>= 1) part += __shfl_xor(part, o, 64);
  if ((t & 63) == 0) tot[t >> 6] = part;
  __syncthreads();
  const float inv = 1.f / fmaxf(tot[0] + tot[1] + tot[2] + tot[3], 1e-16f);

  const int lim = min(16, cb - l0);
  float a0 = 0.f, a1 = 0.f, a2 = 0.f, a3 = 0.f;
  for (int l = 0; l < lim; l++) {
    const int gl = (b << 10) + l0 + l;
    const float wv = __expf(scores[gl]) * inv;
    const s4v v = *(const s4v*)&hallc[(long)gl*1024 + t*4];
    a0 += wv * bf2f((u16)v[0]);
    a1 += wv * bf2f((u16)v[1]);
    a2 += wv * bf2f((u16)v[2]);
    a3 += wv * bf2f((u16)v[3]);
  }
  atomicAdd(&out[(b<<10) + t*4 + 0], a0);
  atomicAdd(&out[(b<<10) + t*4 + 1], a1);
  atomicAdd(&out[(b<<10) + t*4 + 2], a2);
  atomicAdd(&out[(b<<10) + t*4 + 3], a3);
}

// ---------------- launch ----------------
extern "C" void kernel_launch(void* const* d_in, const int* in_sizes, int n_in,
                              void* d_out, int out_size, void* d_ws, size_t ws_size,
                              hipStream_t stream)
{
  const float* hidden = (const float*)d_in[0];
  const int*   mask   = (const int*)d_in[1];
  const float* W0     = (const float*)d_in[2];
  const float* asrc0  = (const float*)d_in[3];
  const float* adst0  = (const float*)d_in[4];
  const float* wed0   = (const float*)d_in[5];
  const float* aed0   = (const float*)d_in[6];
  const float* bias0  = (const float*)d_in[7];
  const float* W1     = (const float*)d_in[8];
  const float* asrc1  = (const float*)d_in[9];
  const float* adst1  = (const float*)d_in[10];
  const float* wed1   = (const float*)d_in[11];
  const float* aed1   = (const float*)d_in[12];
  const float* bias1  = (const float*)d_in[13];
  const float* S1W    = (const float*)d_in[14];
  const float* S1b    = (const float*)d_in[15];
  const float* S2W    = (const float*)d_in[16];
  // S2b cancels in softmax.
  float* out = (float*)d_out;

  char* ws = (char*)d_ws;
  u16* hallc   = (u16*)(ws + 0);                  // 16384x1024 bf16 (32 MB)
  u16* partial = (u16*)(ws + 33554432);           // 16384x512 bf16 (16 MB)
  u16* gt2     = (u16*)(ws + 50331648);           // 16x128x1024 bf16 (4 MB)
  unsigned char* adj = (unsigned char*)(ws + 58720256); // 16 MB
  u16* gt   = (u16*)(ws + 75497472);              // 4 MB
  u16* w0t  = (u16*)(ws + 79691776);
  u16* w1t  = (u16*)(ws + 79888384);
  u16* s1t  = (u16*)(ws + 79921152);
  float* ald = (float*)(ws + 80969728);
  float* als = (float*)(ws + 81035264);
  float* scores = (float*)(ws + 81100800);
  float* als1   = (float*)(ws + 81166336);
  float* ald1   = (float*)(ws + 81231872);
  float* aeb    = (float*)(ws + 81297408);
  int*   cnt    = (int*)(ws + 81297920);
  int*   idxb   = (int*)(ws + 81298432);
  float* u0     = (float*)(ws + 81363968);
  float* v0     = (float*)(ws + 81367040);
  float* u1     = (float*)(ws + 81370112);
  float* v1     = (float*)(ws + 81370624);
  float* rn     = (float*)(ws + 81371136);

  pre_kernel<<<212, 1024, 0, stream>>>(out, scores, W0, w0t, W1, w1t, S1W, s1t,
      wed0, aed0, wed1, aed1, aeb, asrc0, adst0, asrc1, adst1,
      u0, v0, u1, v1, mask, cnt, idxb);

  hn_kernel<<<4096, 256, 0, stream>>>(hidden, cnt, idxb, u0, v0, aeb, hallc, rn, als, ald);

  // sim (symmetric triangle, rn-scaled) + proj0 + scorer K=768 bulk; 64x64 tiles
  mega_kernel<<<4736, 256, 0, stream>>>(hallc, w0t, s1t, rn, adj, gt, partial, cnt);

  // layer 0 (+ fused proj1 -> gt2, als1/ald1)
  gat_attn<1><<<1024, 256, 0, stream>>>(adj, ald, als, gt, bias0, cnt, hallc, 768,
        u1, v1, aeb + 1, als1, ald1, w1t, gt2);

  // layer 1
  gat_attn<0><<<1024, 256, 0, stream>>>(adj, ald1, als1, gt2, bias1, cnt, hallc, 896,
        nullptr, nullptr, nullptr, nullptr, nullptr, nullptr, nullptr);

  // scorer finisher: K=256 + partial + tanh + S2 dot
  scorer_fin<<<2048, 256, 0, stream>>>(hallc, s1t, partial, cnt, S1b, S2W, scores);

  pooled_kernel<<<dim3(64,16), 256, 0, stream>>>(hallc, scores, cnt, out);
}

// Round 15
// 97.389 us; speedup vs baseline: 1.2407x; 1.0041x over previous
//
#include <hip/hip_runtime.h>

typedef __attribute__((ext_vector_type(8))) short short8;
typedef __attribute__((ext_vector_type(4))) short s4v;
typedef __attribute__((ext_vector_type(4))) float f32x4;
typedef unsigned short u16;
typedef unsigned int u32;
typedef unsigned long long u64;

#define TAU_F 0.3f

__device__ __forceinline__ u16 f2bf(float f){
  u32 u = __float_as_uint(f);
  u32 r = u + 0x7FFFu + ((u >> 16) & 1u);
  return (u16)(r >> 16);
}
__device__ __forceinline__ float bf2f(u16 v){
  return __uint_as_float(((u32)v) << 16);
}
__device__ __forceinline__ float tanh_fast(float x){
  const float e = __expf(2.f * x);
  return 1.f - 2.f / (e + 1.f);
}

typedef __attribute__((address_space(1))) const u32 glb_u32;
typedef __attribute__((address_space(3))) u32 lds_u32;
__device__ __forceinline__ void async_lds16(const void* g, void* l){
  __builtin_amdgcn_global_load_lds((glb_u32*)g, (lds_u32*)l, 16, 0, 0);
}

// ---------------- merged preprocessing (one launch) --------------------------
// [0,16) zero out | [16,32) zero scores | [32,56) W0^T | [56,60) W1^T
// [60,188) S1W^T | 188 ae | [189,195) u0/v0 (6 blocks, coalesced) | 195 u1/v1
// [196,212) compaction
__global__ __launch_bounds__(1024)
void pre_kernel(float* __restrict__ out, float* __restrict__ scores,
                const float* __restrict__ W0, u16* __restrict__ w0t,
                const float* __restrict__ W1, u16* __restrict__ w1t,
                const float* __restrict__ S1W, u16* __restrict__ s1t,
                const float* __restrict__ wed0, const float* __restrict__ aed0,
                const float* __restrict__ wed1, const float* __restrict__ aed1,
                float* __restrict__ aeb,
                const float* __restrict__ asrc0, const float* __restrict__ adst0,
                const float* __restrict__ asrc1, const float* __restrict__ adst1,
                float* __restrict__ u0, float* __restrict__ v0,
                float* __restrict__ u1, float* __restrict__ v1,
                const int* __restrict__ mask, int* __restrict__ cnt, int* __restrict__ idxb)
{
  __shared__ float lds[64*65];
  const int blk = blockIdx.x, t = threadIdx.x;

  auto tr_tile = [&](const float* in, u16* o, int K, int N, int kt, int ntile) {
    const int r = t >> 4, c0 = (t & 15) * 4;
    const int k0 = kt*64, n0 = ntile*64;
    const float4 v = *(const float4*)&in[(long)(k0 + r)*N + n0 + c0];
    lds[r*65 + c0 + 0] = v.x; lds[r*65 + c0 + 1] = v.y;
    lds[r*65 + c0 + 2] = v.z; lds[r*65 + c0 + 3] = v.w;
    __syncthreads();
    const u64 pk = (u64)f2bf(lds[(c0+0)*65 + r])
                 | ((u64)f2bf(lds[(c0+1)*65 + r]) << 16)
                 | ((u64)f2bf(lds[(c0+2)*65 + r]) << 32)
                 | ((u64)f2bf(lds[(c0+3)*65 + r]) << 48);
    *(u64*)&o[(long)(n0 + r)*K + k0 + c0] = pk;
  };

  if (blk < 16)  { out[blk*1024 + t] = 0.f; return; }
  if (blk < 32)  { scores[(blk-16)*1024 + t] = 0.f; return; }
  if (blk < 56)  { const int id = blk-32;  tr_tile(W0,  w0t, 768, 128, id >> 1, id & 1); return; }
  if (blk < 60)  { const int id = blk-56;  tr_tile(W1,  w1t, 128, 128, id >> 1, id & 1); return; }
  if (blk < 188) { const int id = blk-60;  tr_tile(S1W, s1t, 1024, 512, id >> 3, id & 7); return; }
  if (blk == 188) {
    if (t < 128) { lds[t] = wed0[t]*aed0[t]; lds[128+t] = wed1[t]*aed1[t]; }
    __syncthreads();
    for (int o = 64; o > 0; o >>= 1) { if (t < o) { lds[t] += lds[t+o]; lds[128+t] += lds[128+t+o]; } __syncthreads(); }
    if (t == 0) { aeb[0] = lds[0]; aeb[1] = lds[128]; }
    return;
  }
  if (blk < 195) {                                   // u0/v0: 6 blocks x 128 rows
    const int q = blk - 189;
    const int row = q*128 + (t >> 3);
    const int c0 = (t & 7) * 16;
    float su = 0.f, sv = 0.f;
#pragma unroll
    for (int i = 0; i < 16; i += 4) {
      const float4 wv = *(const float4*)&W0[row*128 + c0 + i];
      const float4 sa = *(const float4*)&asrc0[c0 + i];
      const float4 da = *(const float4*)&adst0[c0 + i];
      su += wv.x*sa.x + wv.y*sa.y + wv.z*sa.z + wv.w*sa.w;
      sv += wv.x*da.x + wv.y*da.y + wv.z*da.z + wv.w*da.w;
    }
    su += __shfl_xor(su, 1, 64); su += __shfl_xor(su, 2, 64); su += __shfl_xor(su, 4, 64);
    sv += __shfl_xor(sv, 1, 64); sv += __shfl_xor(sv, 2, 64); sv += __shfl_xor(sv, 4, 64);
    if ((t & 7) == 0) { u0[row] = su; v0[row] = sv; }
    return;
  }
  if (blk == 195) {
    if (t < 128) {
      float su = 0.f, sv = 0.f;
      for (int k = 0; k < 128; k++) { const float w = W1[k*128 + t]; su += w*asrc1[k]; sv += w*adst1[k]; }
      u1[t] = su; v1[t] = sv;
    }
    return;
  }
  { // compaction
    int* wtot = (int*)lds;
    int* woff = (int*)lds + 16;
    const int b = blk - 196;
    const int w = t >> 6, lane = t & 63;
    const int m = mask[(b << 10) + t];
    const u64 bal = __ballot(m != 0);
    const int pos = __popcll(bal & ((1ull << lane) - 1ull));
    if (lane == 0) wtot[w] = __popcll(bal);
    __syncthreads();
    if (t == 0) { int a = 0; for (int i = 0; i < 16; i++) { woff[i] = a; a += wtot[i]; } cnt[b] = a; }
    __syncthreads();
    if (m) idxb[(b << 10) + woff[w] + pos] = t;
  }
}

// ---- gather (no normalize store), rnorm, fused layer-0 als/ald --------------
__global__ __launch_bounds__(256)
void hn_kernel(const float* __restrict__ hidden, const int* __restrict__ cnt,
               const int* __restrict__ idx,
               const float* __restrict__ u0, const float* __restrict__ v0,
               const float* __restrict__ aeb,
               u16* __restrict__ hallc, float* __restrict__ rnp,
               float* __restrict__ als, float* __restrict__ ald)
{
  const int gr = blockIdx.x * 4 + (threadIdx.x >> 6);
  const int b = gr >> 10, c = gr & 1023;
  const int lane = threadIdx.x & 63;
  if (c >= cnt[b]) return;
  const int l = idx[gr];
  const float* h = hidden + (long)((b << 10) + l) * 768;
  float x[12]; float ss = 0.f, sa = 0.f, sd = 0.f;
#pragma unroll
  for (int k = 0; k < 12; k++) {
    x[k] = h[k*64 + lane];
    ss += x[k]*x[k];
    sa += x[k]*u0[k*64 + lane];
    sd += x[k]*v0[k*64 + lane];
  }
#pragma unroll
  for (int o = 32; o > 0; o >>= 1) {
    ss += __shfl_xor(ss, o, 64);
    sa += __shfl_xor(sa, o, 64);
    sd += __shfl_xor(sd, o, 64);
  }
  const float inv = 1.f / fmaxf(sqrtf(ss), 1e-8f);
  if (lane == 0) { als[gr] = sa; ald[gr] = sd + aeb[0]; rnp[gr] = inv; }
#pragma unroll
  for (int k = 0; k < 12; k++)
    hallc[(long)gr*1024 + k*64 + lane] = f2bf(x[k]);
}

// ------- mega GEMM launch: 64x64 tiles, BK=64, depth-2 counted-vmcnt pipeline
// [0,2176): sim (XCD-pinned per batch; adj via rn scaling, mirror store)
// [2176,2688): proj0 (hallc @ w0t -> gt)
// [2688,4736): scorer_p0 (hallc[:,0:768] @ s1t[:,0:768] -> bf16 partial)
__global__ __launch_bounds__(256)
void mega_kernel(const u16* __restrict__ hallc, const u16* __restrict__ w0t,
                 const u16* __restrict__ s1t, const float* __restrict__ rn,
                 unsigned char* __restrict__ adjp, u16* __restrict__ gtp,
                 u16* __restrict__ partial, const int* __restrict__ cnt)
{
  __shared__ u16 lA[2][64*64];
  __shared__ u16 lB[2][64*64];
  const int t = threadIdx.x, w = t >> 6, lane = t & 63;
  const int bid = blockIdx.x;
  int mode, bz = 0, i0, n0, lda, ldb, ti = 0, tj = 0, cb = 0;
  const u16 *Ab, *Bb;
  if (bid < 2176) {
    mode = 0;
    const int xcd = bid & 7, s = bid >> 3;
    const int hi = (s >= 136) ? 1 : 0;
    bz = xcd*2 + hi;
    int rem = s - hi*136, width = 16;
    while (rem >= width) { rem -= width; ti++; width--; }
    tj = ti + rem;
    i0 = ti*64; n0 = tj*64;
    cb = cnt[bz];
    if (i0 >= cb || n0 >= cb) return;
    Ab = hallc + (((long)bz << 10) << 10);
    Bb = Ab; lda = 1024; ldb = 1024;
  } else if (bid < 2688) {
    mode = 1;
    const int id = bid - 2176;
    i0 = (((id & 7) << 5) + ((id >> 3) & 31)) * 64;
    n0 = (id >> 8) * 64;
    if ((i0 & 1023) >= cnt[i0 >> 10]) return;
    Ab = hallc; lda = 1024; Bb = w0t; ldb = 768;
  } else {
    mode = 2;
    const int id = bid - 2688;
    i0 = (((id & 7) << 5) + ((id >> 3) & 31)) * 64;
    n0 = (id >> 8) * 64;
    if ((i0 & 1023) >= cnt[i0 >> 10]) return;
    Ab = hallc; lda = 1024; Bb = s1t; ldb = 1024;
  }
  const int wr = w >> 1, wc = w & 1;
  const int srow = t >> 3, scg = t & 7;
  const int sc0 = ((scg ^ (srow & 7)) << 3);
  const long arow0 = (long)(i0 + srow) * lda, arow1 = (long)(i0 + srow + 32) * lda;
  const long brow0 = (long)(n0 + srow) * ldb, brow1 = (long)(n0 + srow + 32) * ldb;
  const int rA = lane & 15, kg = lane >> 4;
  const int sw = rA & 7;
  const int off0 = ((kg ^ sw) << 3);
  const int off1 = (((4 + kg) ^ sw) << 3);
  const int rowA0 = (wr*32 + rA) * 64, rowA1 = (wr*32 + 16 + rA) * 64;
  const int rowB0 = (wc*32 + rA) * 64, rowB1 = (wc*32 + 16 + rA) * 64;
  f32x4 acc[2][2] = {};

  auto stage = [&](int buf, int kt) {
    async_lds16(Ab + arow0 + kt + sc0, &lA[buf][t*8]);
    async_lds16(Ab + arow1 + kt + sc0, &lA[buf][2048 + t*8]);
    async_lds16(Bb + brow0 + kt + sc0, &lB[buf][t*8]);
    async_lds16(Bb + brow1 + kt + sc0, &lB[buf][2048 + t*8]);
  };
  auto compute = [&](int buf) {
    short8 a00 = *(const short8*)&lA[buf][rowA0 + off0];
    short8 a01 = *(const short8*)&lA[buf][rowA0 + off1];
    short8 a10 = *(const short8*)&lA[buf][rowA1 + off0];
    short8 a11 = *(const short8*)&lA[buf][rowA1 + off1];
    short8 b00 = *(const short8*)&lB[buf][rowB0 + off0];
    short8 b01 = *(const short8*)&lB[buf][rowB0 + off1];
    short8 b10 = *(const short8*)&lB[buf][rowB1 + off0];
    short8 b11 = *(const short8*)&lB[buf][rowB1 + off1];
    __builtin_amdgcn_s_setprio(1);
    acc[0][0] = __builtin_amdgcn_mfma_f32_16x16x32_bf16(a00, b00, acc[0][0], 0, 0, 0);
    acc[0][1] = __builtin_amdgcn_mfma_f32_16x16x32_bf16(a00, b10, acc[0][1], 0, 0, 0);
    acc[1][0] = __builtin_amdgcn_mfma_f32_16x16x32_bf16(a10, b00, acc[1][0], 0, 0, 0);
    acc[1][1] = __builtin_amdgcn_mfma_f32_16x16x32_bf16(a10, b10, acc[1][1], 0, 0, 0);
    acc[0][0] = __builtin_amdgcn_mfma_f32_16x16x32_bf16(a01, b01, acc[0][0], 0, 0, 0);
    acc[0][1] = __builtin_amdgcn_mfma_f32_16x16x32_bf16(a01, b11, acc[0][1], 0, 0, 0);
    acc[1][0] = __builtin_amdgcn_mfma_f32_16x16x32_bf16(a11, b01, acc[1][0], 0, 0, 0);
    acc[1][1] = __builtin_amdgcn_mfma_f32_16x16x32_bf16(a11, b11, acc[1][1], 0, 0, 0);
    __builtin_amdgcn_s_setprio(0);
  };

  // depth-2 pipeline: counted vmcnt keeps the next tile's loads in flight
  // across the barrier (never drain to 0 in steady state).
  stage(0, 0);
  stage(1, 64);
  int cur = 0;
  for (int kt = 0; kt < 10; kt++) {
    asm volatile("s_waitcnt vmcnt(4)" ::: "memory");
    __builtin_amdgcn_s_barrier();
    compute(cur);
    __builtin_amdgcn_s_barrier();
    stage(cur, (kt + 2) << 6);
    cur ^= 1;
  }
  asm volatile("s_waitcnt vmcnt(4)" ::: "memory");
  __builtin_amdgcn_s_barrier();
  compute(cur);
  asm volatile("s_waitcnt vmcnt(0)" ::: "memory");
  __builtin_amdgcn_s_barrier();
  compute(cur ^ 1);

#pragma unroll
  for (int m = 0; m < 2; m++) {
    const int gi0 = i0 + wr*32 + m*16 + kg*4;
#pragma unroll
    for (int n = 0; n < 2; n++) {
      const int gj = n0 + wc*32 + n*16 + rA;
#pragma unroll
      for (int r = 0; r < 4; r++) {
        const int gi = gi0 + r;
        const float c = acc[m][n][r];
        if (mode == 0) {
          if (gi < cb && gj < cb) {
            const float sim = c * rn[(bz << 10) + gi] * rn[(bz << 10) + gj];
            const unsigned char e = (sim > TAU_F) ? 1 : 0;
            adjp[((long)bz << 20) + ((long)gi << 10) + gj] = e;
            if (ti != tj) adjp[((long)bz << 20) + ((long)gj << 10) + gi] = e;
          }
        } else if (mode == 1) {
          const int b = gi >> 10, l = gi & 1023;
          gtp[(((long)(b*128 + gj)) << 10) + l] = f2bf(c);
        } else {
          partial[(long)gi * 512 + gj] = f2bf(c);
        }
      }
    }
  }
}

// ------- scorer finisher: K=256, depth-2 pipeline + partial + tanh + S2 dot --
__global__ __launch_bounds__(256)
void scorer_fin(const u16* __restrict__ hallc, const u16* __restrict__ s1t,
                const u16* __restrict__ partial, const int* __restrict__ cnt,
                const float* __restrict__ s1b, const float* __restrict__ s2w,
                float* __restrict__ scoresp)
{
  __shared__ u16 lA[2][64*64];
  __shared__ u16 lB[2][64*64];
  __shared__ float sgrid[64];
  const int t = threadIdx.x, w = t >> 6, lane = t & 63;
  const int id = blockIdx.x;
  const int i0 = (((id & 7) << 5) + ((id >> 3) & 31)) * 64;
  const int n0 = (id >> 8) * 64;
  if ((i0 & 1023) >= cnt[i0 >> 10]) return;
  if (t < 64) sgrid[t] = 0.f;
  const int wr = w >> 1, wc = w & 1;
  const int srow = t >> 3, scg = t & 7;
  const int sc0 = ((scg ^ (srow & 7)) << 3);
  const long arow0 = (long)(i0 + srow) * 1024 + 768, arow1 = (long)(i0 + srow + 32) * 1024 + 768;
  const long brow0 = (long)(n0 + srow) * 1024 + 768, brow1 = (long)(n0 + srow + 32) * 1024 + 768;
  const int rA = lane & 15, kg = lane >> 4;
  const int sw = rA & 7;
  const int off0 = ((kg ^ sw) << 3);
  const int off1 = (((4 + kg) ^ sw) << 3);
  const int rowA0 = (wr*32 + rA) * 64, rowA1 = (wr*32 + 16 + rA) * 64;
  const int rowB0 = (wc*32 + rA) * 64, rowB1 = (wc*32 + 16 + rA) * 64;
  f32x4 acc[2][2] = {};

  auto stage = [&](int buf, int kt) {
    async_lds16(hallc + arow0 + kt + sc0, &lA[buf][t*8]);
    async_lds16(hallc + arow1 + kt + sc0, &lA[buf][2048 + t*8]);
    async_lds16(s1t + brow0 + kt + sc0, &lB[buf][t*8]);
    async_lds16(s1t + brow1 + kt + sc0, &lB[buf][2048 + t*8]);
  };
  auto compute = [&](int buf) {
    short8 a00 = *(const short8*)&lA[buf][rowA0 + off0];
    short8 a01 = *(const short8*)&lA[buf][rowA0 + off1];
    short8 a10 = *(const short8*)&lA[buf][rowA1 + off0];
    short8 a11 = *(const short8*)&lA[buf][rowA1 + off1];
    short8 b00 = *(const short8*)&lB[buf][rowB0 + off0];
    short8 b01 = *(const short8*)&lB[buf][rowB0 + off1];
    short8 b10 = *(const short8*)&lB[buf][rowB1 + off0];
    short8 b11 = *(const short8*)&lB[buf][rowB1 + off1];
    __builtin_amdgcn_s_setprio(1);
    acc[0][0] = __builtin_amdgcn_mfma_f32_16x16x32_bf16(a00, b00, acc[0][0], 0, 0, 0);
    acc[0][1] = __builtin_amdgcn_mfma_f32_16x16x32_bf16(a00, b10, acc[0][1], 0, 0, 0);
    acc[1][0] = __builtin_amdgcn_mfma_f32_16x16x32_bf16(a10, b00, acc[1][0], 0, 0, 0);
    acc[1][1] = __builtin_amdgcn_mfma_f32_16x16x32_bf16(a10, b10, acc[1][1], 0, 0, 0);
    acc[0][0] = __builtin_amdgcn_mfma_f32_16x16x32_bf16(a01, b01, acc[0][0], 0, 0, 0);
    acc[0][1] = __builtin_amdgcn_mfma_f32_16x16x32_bf16(a01, b11, acc[0][1], 0, 0, 0);
    acc[1][0] = __builtin_amdgcn_mfma_f32_16x16x32_bf16(a11, b01, acc[1][0], 0, 0, 0);
    acc[1][1] = __builtin_amdgcn_mfma_f32_16x16x32_bf16(a11, b11, acc[1][1], 0, 0, 0);
    __builtin_amdgcn_s_setprio(0);
  };

  stage(0, 0);
  stage(1, 64);
  int cur = 0;
  for (int kt = 0; kt < 2; kt++) {
    asm volatile("s_waitcnt vmcnt(4)" ::: "memory");
    __builtin_amdgcn_s_barrier();
    compute(cur);
    __builtin_amdgcn_s_barrier();
    stage(cur, (kt + 2) << 6);
    cur ^= 1;
  }
  asm volatile("s_waitcnt vmcnt(4)" ::: "memory");
  __builtin_amdgcn_s_barrier();
  compute(cur);
  asm volatile("s_waitcnt vmcnt(0)" ::: "memory");
  __builtin_amdgcn_s_barrier();
  compute(cur ^ 1);

#pragma unroll
  for (int m = 0; m < 2; m++)
#pragma unroll
    for (int r = 0; r < 4; r++) {
      const int gi = i0 + wr*32 + m*16 + kg*4 + r;
      float contrib = 0.f;
#pragma unroll
      for (int n = 0; n < 2; n++) {
        const int gj = n0 + wc*32 + n*16 + rA;
        const float p = acc[m][n][r] + bf2f(partial[(long)gi*512 + gj]) + s1b[gj];
        contrib += tanh_fast(p) * s2w[gj];
      }
#pragma unroll
      for (int off = 1; off < 16; off <<= 1) contrib += __shfl_xor(contrib, off, 64);
      if (rA == 0) atomicAdd(&sgrid[wr*32 + m*16 + kg*4 + r], contrib);
    }
  __syncthreads();
  if (t < 64) {
    const int gi = i0 + t;
    if ((gi & 1023) < cnt[gi >> 10]) atomicAdd(&scoresp[gi], sgrid[t]);
  }
}

// ---------------- fused GAT attention; FUSE=1 adds als1/ald1 + proj1->gt2 ----
template<int FUSE>
__global__ __launch_bounds__(256)
void gat_attn(const unsigned char* __restrict__ adj,
              const float* __restrict__ ald, const float* __restrict__ als,
              const u16* __restrict__ gT, const float* __restrict__ bias,
              const int* __restrict__ cnt,
              u16* __restrict__ hall, int hall_off,
              const float* __restrict__ u1, const float* __restrict__ v1,
              const float* __restrict__ aeb1,
              float* __restrict__ als_o, float* __restrict__ ald_o,
              const u16* __restrict__ w1t, u16* __restrict__ gt2)
{
  __shared__ float red[4][16][132];
  __shared__ float ssumw[4][16];
  __shared__ float alds[FUSE ? 16 : 1][17], aldd[FUSE ? 16 : 1][17];
  __shared__ u16 h1s[FUSE ? 16 : 1][136];
  const int t = threadIdx.x, w = t >> 6, lane = t & 63;
  const int o = blockIdx.x;
  const int xcd = o & 7, s = o >> 3;
  const int bz = xcd*2 + (s >> 6);
  const int i0 = (s & 63) * 16;
  const int cb = cnt[bz];
  if (i0 >= cb) return;
  const int rr = lane & 15, kg = lane >> 4;
  const int r0 = i0 + rr;
  const bool rvalid = r0 < cb;
  const float ald0 = ald[(bz << 10) + r0];
  const unsigned char* arow = adj + ((long)bz << 20) + ((long)r0 << 10);
  const float* als_b = als + (bz << 10);
  const u16* gTb = gT + ((long)bz << 17);
  float s0 = 0.f;
  f32x4 acc[8] = {};
  const int jbase = w * 256 + kg * 8;

  u64 aw[8];
#pragma unroll
  for (int it = 0; it < 8; it++) {
    const int jl = jbase + it*32;
    u64 a = 0;
    if (rvalid && jl < cb) {
      a = *(const u64*)(arow + jl);
      const int rem = cb - jl;
      if (rem < 8) a &= (1ull << (rem * 8)) - 1ull;
    }
    aw[it] = a;
  }

#pragma unroll
  for (int it = 0; it < 8; it++) {
    const u64 a0 = aw[it];
    if (__any(a0 != 0ull)) {
      const int jl = jbase + it*32;
      const float4 f0 = *(const float4*)(als_b + jl);
      const float4 f1 = *(const float4*)(als_b + jl + 4);
      const float sv[8] = {f0.x, f0.y, f0.z, f0.w, f1.x, f1.y, f1.z, f1.w};
      short8 pa;
#pragma unroll
      for (int e = 0; e < 8; e++) {
        float x = ald0 + sv[e];
        x = x > 0.f ? x : 0.2f * x;
        const float p = ((a0 >> (8*e)) & 255ull) ? __expf(x) : 0.f;
        s0 += p;
        pa[e] = (short)f2bf(p);
      }
      __builtin_amdgcn_s_setprio(1);
#pragma unroll
      for (int nf = 0; nf < 8; nf++) {
        const short8 b = *(const short8*)&gTb[(long)(nf*16 + rr) * 1024 + jl];
        acc[nf] = __builtin_amdgcn_mfma_f32_16x16x32_bf16(pa, b, acc[nf], 0, 0, 0);
      }
      __builtin_amdgcn_s_setprio(0);
    }
  }

  s0 += __shfl_xor(s0, 16, 64);
  s0 += __shfl_xor(s0, 32, 64);
  if (lane < 16) ssumw[w][lane] = s0;
#pragma unroll
  for (int nf = 0; nf < 8; nf++)
#pragma unroll
    for (int rg = 0; rg < 4; rg++)
      red[w][kg*4 + rg][nf*16 + rr] = acc[nf][rg];
  __syncthreads();

  const int r = t >> 4, c0 = (t & 15) * 8;
  const float sm = ssumw[0][r] + ssumw[1][r] + ssumw[2][r] + ssumw[3][r];
  const float inv = sm > 0.f ? 1.f / sm : 0.f;
  const long gi = ((long)bz << 10) + i0 + r;
  u16* orow = hall + gi * 1024 + hall_off;
  short8 hv;
  float pa_s = 0.f, pa_d = 0.f;
#pragma unroll
  for (int q = 0; q < 8; q++) {
    const int c = c0 + q;
    float v = (red[0][r][c] + red[1][r][c] + red[2][r][c] + red[3][r][c]) * inv + bias[c];
    v = v > 0.f ? v : 0.f;
    hv[q] = (short)f2bf(v);
    if (FUSE) { pa_s += v * u1[c]; pa_d += v * v1[c]; }
  }
  *(short8*)&orow[c0] = hv;
  if (FUSE) {
    *(short8*)&h1s[r][c0] = hv;
    alds[r][t & 15] = pa_s;
    aldd[r][t & 15] = pa_d;
    __syncthreads();
    if (t < 16) {
      float s2 = 0.f, d2 = 0.f;
#pragma unroll
      for (int j = 0; j < 16; j++) { s2 += alds[t][j]; d2 += aldd[t][j]; }
      als_o[(bz << 10) + i0 + t] = s2;
      ald_o[(bz << 10) + i0 + t] = d2 + aeb1[0];
    }
    // proj1: gt2 rows i0..i0+15 = h1s(16x128) @ W1; wave w covers cols [w*32,w*32+32)
    f32x4 pacc[2] = {};
    short8 paf[4];
#pragma unroll
    for (int ks = 0; ks < 4; ks++)
      paf[ks] = *(const short8*)&h1s[lane & 15][ks*32 + kg*8];
#pragma unroll
    for (int n = 0; n < 2; n++) {
      const int col = w*32 + n*16 + (lane & 15);
#pragma unroll
      for (int ks = 0; ks < 4; ks++) {
        const short8 pb = *(const short8*)&w1t[col*128 + ks*32 + kg*8];
        pacc[n] = __builtin_amdgcn_mfma_f32_16x16x32_bf16(paf[ks], pb, pacc[n], 0, 0, 0);
      }
    }
#pragma unroll
    for (int n = 0; n < 2; n++) {
      const int gj = w*32 + n*16 + (lane & 15);
#pragma unroll
      for (int rg = 0; rg < 4; rg++)
        gt2[(((long)(bz*128 + gj)) << 10) + i0 + kg*4 + rg] = f2bf(pacc[n][rg]);
    }
  }
}

// ---------------- pooled: softmax + weighted sum of bf16 hallc rows ----------
__global__ __launch_bounds__(256)
void pooled_kernel(const u16* __restrict__ hallc, const float* __restrict__ scores,
                   const int* __restrict__ cnt, float* __restrict__ out)
{
  __shared__ float tot[4];
  const int b = blockIdx.y, l0 = blockIdx.x * 16, t = threadIdx.x;
  const int cb = cnt[b];
  if (l0 >= cb) return;
  float part = 0.f;
#pragma unroll
  for (int q = 0; q < 4; q++) {
    const int l = q*256 + t;
    if (l < cb) part += __expf(scores[(b << 10) + l]);
  }
#pragma unroll
  for (int o = 32; o > 0; o >>= 1) part += __shfl_xor(part, o, 64);
  if ((t & 63) == 0) tot[t >> 6] = part;
  __syncthreads();
  const float inv = 1.f / fmaxf(tot[0] + tot[1] + tot[2] + tot[3], 1e-16f);

  const int lim = min(16, cb - l0);
  float a0 = 0.f, a1 = 0.f, a2 = 0.f, a3 = 0.f;
  for (int l = 0; l < lim; l++) {
    const int gl = (b << 10) + l0 + l;
    const float wv = __expf(scores[gl]) * inv;
    const s4v v = *(const s4v*)&hallc[(long)gl*1024 + t*4];
    a0 += wv * bf2f((u16)v[0]);
    a1 += wv * bf2f((u16)v[1]);
    a2 += wv * bf2f((u16)v[2]);
    a3 += wv * bf2f((u16)v[3]);
  }
  atomicAdd(&out[(b<<10) + t*4 + 0], a0);
  atomicAdd(&out[(b<<10) + t*4 + 1], a1);
  atomicAdd(&out[(b<<10) + t*4 + 2], a2);
  atomicAdd(&out[(b<<10) + t*4 + 3], a3);
}

// ---------------- launch ----------------
extern "C" void kernel_launch(void* const* d_in, const int* in_sizes, int n_in,
                              void* d_out, int out_size, void* d_ws, size_t ws_size,
                              hipStream_t stream)
{
  const float* hidden = (const float*)d_in[0];
  const int*   mask   = (const int*)d_in[1];
  const float* W0     = (const float*)d_in[2];
  const float* asrc0  = (const float*)d_in[3];
  const float* adst0  = (const float*)d_in[4];
  const float* wed0   = (const float*)d_in[5];
  const float* aed0   = (const float*)d_in[6];
  const float* bias0  = (const float*)d_in[7];
  const float* W1     = (const float*)d_in[8];
  const float* asrc1  = (const float*)d_in[9];
  const float* adst1  = (const float*)d_in[10];
  const float* wed1   = (const float*)d_in[11];
  const float* aed1   = (const float*)d_in[12];
  const float* bias1  = (const float*)d_in[13];
  const float* S1W    = (const float*)d_in[14];
  const float* S1b    = (const float*)d_in[15];
  const float* S2W    = (const float*)d_in[16];
  // S2b cancels in softmax.
  float* out = (float*)d_out;

  char* ws = (char*)d_ws;
  u16* hallc   = (u16*)(ws + 0);                  // 16384x1024 bf16 (32 MB)
  u16* partial = (u16*)(ws + 33554432);           // 16384x512 bf16 (16 MB)
  u16* gt2     = (u16*)(ws + 50331648);           // 16x128x1024 bf16 (4 MB)
  unsigned char* adj = (unsigned char*)(ws + 58720256); // 16 MB
  u16* gt   = (u16*)(ws + 75497472);              // 4 MB
  u16* w0t  = (u16*)(ws + 79691776);
  u16* w1t  = (u16*)(ws + 79888384);
  u16* s1t  = (u16*)(ws + 79921152);
  float* ald = (float*)(ws + 80969728);
  float* als = (float*)(ws + 81035264);
  float* scores = (float*)(ws + 81100800);
  float* als1   = (float*)(ws + 81166336);
  float* ald1   = (float*)(ws + 81231872);
  float* aeb    = (float*)(ws + 81297408);
  int*   cnt    = (int*)(ws + 81297920);
  int*   idxb   = (int*)(ws + 81298432);
  float* u0     = (float*)(ws + 81363968);
  float* v0     = (float*)(ws + 81367040);
  float* u1     = (float*)(ws + 81370112);
  float* v1     = (float*)(ws + 81370624);
  float* rn     = (float*)(ws + 81371136);

  pre_kernel<<<212, 1024, 0, stream>>>(out, scores, W0, w0t, W1, w1t, S1W, s1t,
      wed0, aed0, wed1, aed1, aeb, asrc0, adst0, asrc1, adst1,
      u0, v0, u1, v1, mask, cnt, idxb);

  hn_kernel<<<4096, 256, 0, stream>>>(hidden, cnt, idxb, u0, v0, aeb, hallc, rn, als, ald);

  // sim (symmetric triangle, rn-scaled) + proj0 + scorer K=768 bulk; 64x64 tiles
  mega_kernel<<<4736, 256, 0, stream>>>(hallc, w0t, s1t, rn, adj, gt, partial, cnt);

  // layer 0 (+ fused proj1 -> gt2, als1/ald1)
  gat_attn<1><<<1024, 256, 0, stream>>>(adj, ald, als, gt, bias0, cnt, hallc, 768,
        u1, v1, aeb + 1, als1, ald1, w1t, gt2);

  // layer 1
  gat_attn<0><<<1024, 256, 0, stream>>>(adj, ald1, als1, gt2, bias1, cnt, hallc, 896,
        nullptr, nullptr, nullptr, nullptr, nullptr, nullptr, nullptr);

  // scorer finisher: K=256 + partial + tanh + S2 dot (depth-2 pipeline)
  scorer_fin<<<2048, 256, 0, stream>>>(hallc, s1t, partial, cnt, S1b, S2W, scores);

  pooled_kernel<<<dim3(64,16), 256, 0, stream>>>(hallc, scores, cnt, out);
}